// Round 11
// baseline (202.890 us; speedup 1.0000x reference)
//
#include <hip/hip_runtime.h>
#include <hip/hip_bf16.h>

#define S_LEN 2048
#define D_DIM 1024
#define NHEAD 16
#define HDIM  64
#define BATCH 4
#define MROWS (BATCH*S_LEN)   /* 8192 */

typedef short bf16x8 __attribute__((ext_vector_type(8)));
typedef float f32x4  __attribute__((ext_vector_type(4)));
typedef float f32x16 __attribute__((ext_vector_type(16)));
typedef unsigned short u16;

#if __has_builtin(__builtin_amdgcn_exp2f)
#define EXP2(x) __builtin_amdgcn_exp2f(x)
#else
#define EXP2(x) __expf((x) * 0.6931471805599453f)
#endif

#define BAR() asm volatile("s_barrier" ::: "memory")
#define WAITV0() asm volatile("s_waitcnt vmcnt(0)" ::: "memory")
#define QSCALE 0.1803368801111137f   /* (1/8) * log2(e) */

__device__ inline u16 f2bf(float f) {
  union { float f; unsigned u; } v; v.f = f;
  unsigned r = v.u + 0x7fff + ((v.u >> 16) & 1);   // RNE
  return (u16)(r >> 16);
}

__device__ inline unsigned cvtpk(float lo, float hi_) {
  unsigned d;
  asm("v_cvt_pk_bf16_f32 %0, %1, %2" : "=v"(d) : "v"(lo), "v"(hi_));
  return d;
}

__device__ inline void perm32swap(unsigned& a, unsigned& b) {
  asm volatile("v_permlane32_swap_b32 %0, %1" : "+v"(a), "+v"(b));
}

__device__ inline void gload_lds16(const void* g, void* l) {
  __builtin_amdgcn_global_load_lds(
      (const __attribute__((address_space(1))) void*)g,
      (__attribute__((address_space(3))) void*)l, 16, 0, 0);
}

// ---------------- fp32 -> bf16 convert (vectorized) ----------------
__global__ void cvt_x_kernel(const float* __restrict__ x, u16* __restrict__ xb, int n4) {
  int i = blockIdx.x * 256 + threadIdx.x;
  if (i >= n4) return;
  float4 v = reinterpret_cast<const float4*>(x)[i];
  ushort4 o;
  o.x = f2bf(v.x); o.y = f2bf(v.y); o.z = f2bf(v.z); o.w = f2bf(v.w);
  reinterpret_cast<ushort4*>(xb)[i] = o;
}

// ---------------- all-weights transpose: W[K][N] fp32 -> Wt[N][K] bf16 ----------------
// z==0 (Wq) is PRE-SCALED by QSCALE so Q = X*Wq comes out softmax-scaled for free.
__global__ void transpose_w4_kernel(const float* __restrict__ wq, const float* __restrict__ wk,
                                    const float* __restrict__ wv, const float* __restrict__ wo,
                                    u16* __restrict__ wqkvT, u16* __restrict__ woT) {
  __shared__ float t[32][33];
  int z = blockIdx.z;
  const float* w = (z == 0) ? wq : (z == 1) ? wk : (z == 2) ? wv : wo;
  u16* wt = (z < 3) ? (wqkvT + (size_t)z * 1024 * 1024) : woT;
  const float sc = (z == 0) ? QSCALE : 1.0f;
  int tx = threadIdx.x, ty = threadIdx.y;
  int n0 = blockIdx.x * 32, k0 = blockIdx.y * 32;
#pragma unroll
  for (int j = 0; j < 32; j += 8)
    t[ty + j][tx] = w[(size_t)(k0 + ty + j) * D_DIM + n0 + tx];
  __syncthreads();
#pragma unroll
  for (int j = 0; j < 32; j += 8)
    wt[(size_t)(n0 + ty + j) * D_DIM + k0 + tx] = f2bf(t[tx][ty + j] * sc);
}

// ============ QKV GEMM: 128x128, single-buffer 2-sync (R6 body, VGPR 76) ============
__global__ __launch_bounds__(256) void gemm_qkv_kernel(
    const u16* __restrict__ A, const u16* __restrict__ Bt,
    u16* __restrict__ Qb, u16* __restrict__ KP, u16* __restrict__ VP) {
  __shared__ u16 lA[128 * 32];
  __shared__ u16 lB[128 * 32];
  const int tid = threadIdx.x, wid = tid >> 6, lane = tid & 63;
  const int bm = blockIdx.y, bn = blockIdx.x;
  const int fr = lane & 15, fq = lane >> 4;
  const int r0 = wid * 32;
  const int srow = lane >> 2, scol = (lane & 3) * 8;
  const u16* gA = A + (size_t)(bm * 128 + r0 + srow) * 1024 + scol;
  const u16* gB = Bt + (size_t)(bn * 128 + r0 + srow) * 1024 + scol;
  u16* lA0 = &lA[r0 * 32];
  u16* lB0 = &lB[r0 * 32];

  f32x4 acc[4][4] = {};
  const int wm = (wid >> 1) * 64, wn = (wid & 1) * 64;

  for (int k0 = 0; k0 < 1024; k0 += 32) {
    gload_lds16(gA + k0,             lA0);
    gload_lds16(gA + k0 + 16 * 1024, lA0 + 16 * 32);
    gload_lds16(gB + k0,             lB0);
    gload_lds16(gB + k0 + 16 * 1024, lB0 + 16 * 32);
    __syncthreads();
    bf16x8 fa[4], fb[4];
#pragma unroll
    for (int i = 0; i < 4; i++) {
      fa[i] = *(const bf16x8*)&lA[(wm + i * 16 + fr) * 32 + fq * 8];
      fb[i] = *(const bf16x8*)&lB[(wn + i * 16 + fr) * 32 + fq * 8];
    }
#pragma unroll
    for (int i = 0; i < 4; i++)
#pragma unroll
      for (int j = 0; j < 4; j++)
        acc[i][j] = __builtin_amdgcn_mfma_f32_16x16x32_bf16(fa[i], fb[j], acc[i][j], 0, 0, 0);
    __syncthreads();
  }

  const int col0 = bn * 128;   // wave-uniform region select
  if (col0 < 1024) {
#pragma unroll
    for (int i = 0; i < 4; i++)
#pragma unroll
      for (int j = 0; j < 4; j++)
#pragma unroll
        for (int r = 0; r < 4; r++) {
          int row = bm * 128 + wm + i * 16 + fq * 4 + r;
          int col = col0 + wn + j * 16 + fr;
          Qb[(size_t)row * 1024 + col] = f2bf(acc[i][j][r]);
        }
  } else if (col0 < 2048) {
#pragma unroll
    for (int i = 0; i < 4; i++)
#pragma unroll
      for (int j = 0; j < 4; j++) {
        int col = col0 + wn + j * 16 + fr;
        int ck = col - 1024;
        int h = ck >> 6, d = ck & 63;
        int sfr = d >> 4, e = d & 7, hb = (d >> 3) & 1;
#pragma unroll
        for (int r = 0; r < 4; r++) {
          int row = bm * 128 + wm + i * 16 + fq * 4 + r;
          int b = row >> 11, sp = row & 2047;
          int bh = b * 16 + h, jt = sp >> 5;
          int lanep = (sp & 31) + 32 * hb;
          KP[((size_t)(bh * 64 + jt) * 4 + sfr) * 512 + lanep * 8 + e] = f2bf(acc[i][j][r]);
        }
      }
  } else {
#pragma unroll
    for (int i = 0; i < 4; i++)
#pragma unroll
      for (int j = 0; j < 4; j++) {
        int col = col0 + wn + j * 16 + fr;
        int cv = col - 2048;
        int h = cv >> 6, d = cv & 63;
        int R0 = bm * 128 + wm + i * 16 + fq * 4;
        int b = R0 >> 11, sp0 = R0 & 2047;
        int bh = b * 16 + h, jt = sp0 >> 5;
        int c = (d >> 5) * 2 + ((sp0 >> 4) & 1);
        int lanep = (d & 31) + 32 * ((sp0 >> 3) & 1);
        int e0 = sp0 & 7;
        ushort4 ov;
        ov.x = f2bf(acc[i][j][0]); ov.y = f2bf(acc[i][j][1]);
        ov.z = f2bf(acc[i][j][2]); ov.w = f2bf(acc[i][j][3]);
        *(ushort4*)(VP + ((size_t)(bh * 64 + jt) * 4 + c) * 512 + lanep * 8 + e0) = ov;
      }
  }
}

// ============ out-proj GEMM: 128x128, dbuf one-barrier (R7-measured) ============
__global__ __launch_bounds__(256) void gemm_out_kernel(
    const u16* __restrict__ A, const u16* __restrict__ Bt,
    float* __restrict__ C, const float* __restrict__ bias) {
  __shared__ u16 lA[2][128 * 32];
  __shared__ u16 lB[2][128 * 32];
  const int tid = threadIdx.x, wid = tid >> 6, lane = tid & 63;
  const int bm = blockIdx.y, bn = blockIdx.x;
  const int fr = lane & 15, fq = lane >> 4;
  const int r0 = wid * 32;
  const int srow = lane >> 2, scol = (lane & 3) * 8;
  const u16* gA = A + (size_t)(bm * 128 + r0 + srow) * 1024 + scol;
  const u16* gB = Bt + (size_t)(bn * 128 + r0 + srow) * 1024 + scol;

  f32x4 acc[4][4] = {};
  const int wm = (wid >> 1) * 64, wn = (wid & 1) * 64;

  gload_lds16(gA,             &lA[0][r0 * 32]);
  gload_lds16(gA + 16 * 1024, &lA[0][r0 * 32 + 16 * 32]);
  gload_lds16(gB,             &lB[0][r0 * 32]);
  gload_lds16(gB + 16 * 1024, &lB[0][r0 * 32 + 16 * 32]);
  WAITV0();
  BAR();

#pragma unroll
  for (int k0 = 0; k0 < 1024; k0 += 32) {
    const int cur = (k0 >> 5) & 1, nxt = cur ^ 1;
    if (k0 + 32 < 1024) {
      gload_lds16(gA + k0 + 32,             &lA[nxt][r0 * 32]);
      gload_lds16(gA + k0 + 32 + 16 * 1024, &lA[nxt][r0 * 32 + 16 * 32]);
      gload_lds16(gB + k0 + 32,             &lB[nxt][r0 * 32]);
      gload_lds16(gB + k0 + 32 + 16 * 1024, &lB[nxt][r0 * 32 + 16 * 32]);
    }
    bf16x8 fa[4], fb[4];
#pragma unroll
    for (int i = 0; i < 4; i++) {
      fa[i] = *(const bf16x8*)&lA[cur][(wm + i * 16 + fr) * 32 + fq * 8];
      fb[i] = *(const bf16x8*)&lB[cur][(wn + i * 16 + fr) * 32 + fq * 8];
    }
#pragma unroll
    for (int i = 0; i < 4; i++)
#pragma unroll
      for (int j = 0; j < 4; j++)
        acc[i][j] = __builtin_amdgcn_mfma_f32_16x16x32_bf16(fa[i], fb[j], acc[i][j], 0, 0, 0);
    WAITV0();
    BAR();
  }

#pragma unroll
  for (int i = 0; i < 4; i++)
#pragma unroll
    for (int j = 0; j < 4; j++)
#pragma unroll
      for (int r = 0; r < 4; r++) {
        int row = bm * 128 + wm + i * 16 + fq * 4 + r;
        int col = bn * 128 + wn + j * 16 + fr;
        C[(size_t)row * 1024 + col] = acc[i][j][r] + bias[col];
      }
}

// ---------------- softmax + PV step (in-place on sa) ----------------
__device__ __forceinline__ void sm_pv(f32x16& sa, float& m, float& l,
                                      f32x16& acc0, f32x16& acc1,
                                      bf16x8 vf00, bf16x8 vf01,
                                      bf16x8 vf10, bf16x8 vf11) {
  float x8[8], x4[4];
#pragma unroll
  for (int i = 0; i < 8; ++i) x8[i] = fmaxf(sa[2 * i], sa[2 * i + 1]);
#pragma unroll
  for (int i = 0; i < 4; ++i) x4[i] = fmaxf(x8[2 * i], x8[2 * i + 1]);
  float pm = fmaxf(fmaxf(x4[0], x4[1]), fmaxf(x4[2], x4[3]));
  pm = fmaxf(pm, __shfl_xor(pm, 32));

  if (__any(pm > m + 11.5f)) {   // defer-max, THR=8 nats in log2 units
    float mn = fmaxf(m, pm);
    float sc = EXP2(m - mn);
    l *= sc;
#pragma unroll
    for (int r = 0; r < 16; ++r) { acc0[r] *= sc; acc1[r] *= sc; }
    m = mn;
  }

  float rs = 0.f;
#pragma unroll
  for (int r = 0; r < 16; ++r) { sa[r] = EXP2(sa[r] - m); rs += sa[r]; }
  rs += __shfl_xor(rs, 32);
  l += rs;

  unsigned c0 = cvtpk(sa[0],  sa[1]),  c1 = cvtpk(sa[2],  sa[3]);
  unsigned c2 = cvtpk(sa[4],  sa[5]),  c3 = cvtpk(sa[6],  sa[7]);
  unsigned c4 = cvtpk(sa[8],  sa[9]),  c5 = cvtpk(sa[10], sa[11]);
  unsigned c6 = cvtpk(sa[12], sa[13]), c7 = cvtpk(sa[14], sa[15]);
  perm32swap(c0, c2); perm32swap(c1, c3);
  perm32swap(c4, c6); perm32swap(c5, c7);
  union U4 { unsigned u[4]; bf16x8 v; } F0, F1;
  F0.u[0] = c0; F0.u[1] = c1; F0.u[2] = c2; F0.u[3] = c3;
  F1.u[0] = c4; F1.u[1] = c5; F1.u[2] = c6; F1.u[3] = c7;

  __builtin_amdgcn_s_setprio(1);
  acc0 = __builtin_amdgcn_mfma_f32_32x32x16_bf16(vf00, F0.v, acc0, 0, 0, 0);
  acc0 = __builtin_amdgcn_mfma_f32_32x32x16_bf16(vf01, F1.v, acc0, 0, 0, 0);
  acc1 = __builtin_amdgcn_mfma_f32_32x32x16_bf16(vf10, F0.v, acc1, 0, 0, 0);
  acc1 = __builtin_amdgcn_mfma_f32_32x32x16_bf16(vf11, F1.v, acc1, 0, 0, 0);
  __builtin_amdgcn_s_setprio(0);
}

__device__ __forceinline__ void attn_store(u16* Orow, const f32x16& a0,
                                           const f32x16& a1, float inv, int hi) {
#pragma unroll
  for (int g = 0; g < 4; ++g) {
    ushort4 o4;
    o4.x = f2bf(a0[g * 4 + 0] * inv); o4.y = f2bf(a0[g * 4 + 1] * inv);
    o4.z = f2bf(a0[g * 4 + 2] * inv); o4.w = f2bf(a0[g * 4 + 3] * inv);
    *(ushort4*)(Orow + 8 * g + 4 * hi) = o4;
  }
#pragma unroll
  for (int g = 0; g < 4; ++g) {
    ushort4 o4;
    o4.x = f2bf(a1[g * 4 + 0] * inv); o4.y = f2bf(a1[g * 4 + 1] * inv);
    o4.z = f2bf(a1[g * 4 + 2] * inv); o4.w = f2bf(a1[g * 4 + 3] * inv);
    *(ushort4*)(Orow + 32 + 8 * g + 4 * hi) = o4;
  }
}

// ---------------- flash attention (causal), PAIRED q-blocks ----------------
// Block handles q-blocks p and 15-p (work = const across blocks; 512 blocks = 2/CU).
// Shared K/V fragment loads feed BOTH q-sets over the common prefix.
__global__ __launch_bounds__(256) void attn_kernel(
    const u16* __restrict__ Q, const u16* __restrict__ KP,
    const u16* __restrict__ VP, u16* __restrict__ O) {
  const int tid = threadIdx.x, wid = tid >> 6, lane = tid & 63;
  const int lq = lane & 31, hi = lane >> 5;
  int f = blockIdx.x;                   // [0,512)
  int xcd = f & 7, kk = f >> 3;
  int bh = xcd * 8 + (kk & 7);
  int p  = kk >> 3;                     // [0,8): pair (p, 15-p)
  int b = bh >> 4, h = bh & 15;
  const int qL = p * 128 + wid * 32 + lq;
  const int qH = (15 - p) * 128 + wid * 32 + lq;

  const u16* QrowL = Q + (size_t)(b * S_LEN + qL) * D_DIM + h * HDIM;
  const u16* QrowH = Q + (size_t)(b * S_LEN + qH) * D_DIM + h * HDIM;
  bf16x8 qfL[4], qfH[4];
#pragma unroll
  for (int s = 0; s < 4; s++) {
    qfL[s] = *(const bf16x8*)(QrowL + s * 16 + hi * 8);
    qfH[s] = *(const bf16x8*)(QrowH + s * 16 + hi * 8);
  }

  const bf16x8* KPt = (const bf16x8*)KP + (size_t)bh * 64 * 4 * 64;
  const bf16x8* VPt = (const bf16x8*)VP + (size_t)bh * 64 * 4 * 64;

  f32x16 aL0 = {}, aL1 = {}, aH0 = {}, aH1 = {};
  float mL = -3.0e38f, lL = 0.f, mH = -3.0e38f, lH = 0.f;
  const int ntL = 4 * p + wid + 1;
  const int ntH = 60 - 4 * p + wid + 1;   // ntH > ntL always (p<8)

  // ---- phase 1: common prefix, K/V loaded once, both q-sets ----
  for (int t = 0; t < ntL; ++t) {
    const size_t fb = (size_t)t * 4 * 64 + lane;
    bf16x8 kf0 = KPt[fb], kf1 = KPt[fb + 64], kf2 = KPt[fb + 128], kf3 = KPt[fb + 192];
    bf16x8 vf00 = VPt[fb], vf01 = VPt[fb + 64], vf10 = VPt[fb + 128], vf11 = VPt[fb + 192];

    f32x16 saL = {}, saH = {};
    __builtin_amdgcn_s_setprio(1);
    saL = __builtin_amdgcn_mfma_f32_32x32x16_bf16(kf0, qfL[0], saL, 0, 0, 0);
    saH = __builtin_amdgcn_mfma_f32_32x32x16_bf16(kf0, qfH[0], saH, 0, 0, 0);
    saL = __builtin_amdgcn_mfma_f32_32x32x16_bf16(kf1, qfL[1], saL, 0, 0, 0);
    saH = __builtin_amdgcn_mfma_f32_32x32x16_bf16(kf1, qfH[1], saH, 0, 0, 0);
    saL = __builtin_amdgcn_mfma_f32_32x32x16_bf16(kf2, qfL[2], saL, 0, 0, 0);
    saH = __builtin_amdgcn_mfma_f32_32x32x16_bf16(kf2, qfH[2], saH, 0, 0, 0);
    saL = __builtin_amdgcn_mfma_f32_32x32x16_bf16(kf3, qfL[3], saL, 0, 0, 0);
    saH = __builtin_amdgcn_mfma_f32_32x32x16_bf16(kf3, qfH[3], saH, 0, 0, 0);
    __builtin_amdgcn_s_setprio(0);

    if (t == ntL - 1) {   // low diagonal tile
      const int j0 = t * 32;
#pragma unroll
      for (int r = 0; r < 16; ++r) {
        int kidx = j0 + (r & 3) + 8 * (r >> 2) + 4 * hi;
        if (kidx > qL) saL[r] = -3.0e38f;
      }
    }
    sm_pv(saL, mL, lL, aL0, aL1, vf00, vf01, vf10, vf11);
    sm_pv(saH, mH, lH, aH0, aH1, vf00, vf01, vf10, vf11);
  }

  // ---- phase 2: high-only tail ----
  for (int t = ntL; t < ntH; ++t) {
    const size_t fb = (size_t)t * 4 * 64 + lane;
    bf16x8 kf0 = KPt[fb], kf1 = KPt[fb + 64], kf2 = KPt[fb + 128], kf3 = KPt[fb + 192];
    bf16x8 vf00 = VPt[fb], vf01 = VPt[fb + 64], vf10 = VPt[fb + 128], vf11 = VPt[fb + 192];

    f32x16 saH = {};
    __builtin_amdgcn_s_setprio(1);
    saH = __builtin_amdgcn_mfma_f32_32x32x16_bf16(kf0, qfH[0], saH, 0, 0, 0);
    saH = __builtin_amdgcn_mfma_f32_32x32x16_bf16(kf1, qfH[1], saH, 0, 0, 0);
    saH = __builtin_amdgcn_mfma_f32_32x32x16_bf16(kf2, qfH[2], saH, 0, 0, 0);
    saH = __builtin_amdgcn_mfma_f32_32x32x16_bf16(kf3, qfH[3], saH, 0, 0, 0);
    __builtin_amdgcn_s_setprio(0);

    if (t == ntH - 1) {   // high diagonal tile
      const int j0 = t * 32;
#pragma unroll
      for (int r = 0; r < 16; ++r) {
        int kidx = j0 + (r & 3) + 8 * (r >> 2) + 4 * hi;
        if (kidx > qH) saH[r] = -3.0e38f;
      }
    }
    sm_pv(saH, mH, lH, aH0, aH1, vf00, vf01, vf10, vf11);
  }

  attn_store(O + (size_t)(b * S_LEN + qL) * D_DIM + h * HDIM, aL0, aL1, 1.f / lL, hi);
  attn_store(O + (size_t)(b * S_LEN + qH) * D_DIM + h * HDIM, aH0, aH1, 1.f / lH, hi);
}

// ---------------- launcher ----------------
extern "C" void kernel_launch(void* const* d_in, const int* in_sizes, int n_in,
                              void* d_out, int out_size, void* d_ws, size_t ws_size,
                              hipStream_t stream) {
  const float* x  = (const float*)d_in[0];
  const float* wq = (const float*)d_in[1];
  const float* wk = (const float*)d_in[2];
  const float* wv = (const float*)d_in[3];
  const float* wo = (const float*)d_in[4];
  const float* ob = (const float*)d_in[5];
  float* out = (float*)d_out;

  char* ws = (char*)d_ws;
  u16* Xb    = (u16*)(ws);                              // slot A: Xb then Ab
  u16* Ab    = (u16*)(ws);
  u16* Qb    = (u16*)(ws + (size_t)16 * 1024 * 1024);   // 16 MB
  u16* KPb   = (u16*)(ws + (size_t)32 * 1024 * 1024);   // 16 MB
  u16* VPb   = (u16*)(ws + (size_t)48 * 1024 * 1024);   // 16 MB
  u16* WqkvT = (u16*)(ws + (size_t)64 * 1024 * 1024);   // 6 MB
  u16* WoT   = (u16*)(ws + (size_t)70 * 1024 * 1024);   // 2 MB

  cvt_x_kernel<<<(MROWS * D_DIM / 4) / 256, 256, 0, stream>>>(x, Xb, MROWS * D_DIM / 4);

  transpose_w4_kernel<<<dim3(32, 32, 4), dim3(32, 8), 0, stream>>>(
      wq, wk, wv, wo, WqkvT, WoT);

  // fused QKV projection [8192,1024]x[1024,3072] with fused Q/K/V pack epilogue
  gemm_qkv_kernel<<<dim3(24, 64), 256, 0, stream>>>(Xb, WqkvT, Qb, KPb, VPb);

  // paired-causal attention: 512 equal-work blocks
  attn_kernel<<<dim3(512), 256, 0, stream>>>(Qb, KPb, VPb, Ab);

  // out projection [8192,1024]x[1024,1024] + bias, fp32 out
  gemm_out_kernel<<<dim3(8, 64), 256, 0, stream>>>(Ab, WoT, out, ob);
}

// Round 12
// 180.870 us; speedup vs baseline: 1.1217x; 1.1217x over previous
//
#include <hip/hip_runtime.h>
#include <hip/hip_bf16.h>

#define S_LEN 2048
#define D_DIM 1024
#define NHEAD 16
#define HDIM  64
#define BATCH 4
#define MROWS (BATCH*S_LEN)   /* 8192 */

typedef short bf16x8 __attribute__((ext_vector_type(8)));
typedef float f32x4  __attribute__((ext_vector_type(4)));
typedef float f32x16 __attribute__((ext_vector_type(16)));
typedef unsigned short u16;

#if __has_builtin(__builtin_amdgcn_exp2f)
#define EXP2(x) __builtin_amdgcn_exp2f(x)
#else
#define EXP2(x) __expf((x) * 0.6931471805599453f)
#endif

#define BAR() asm volatile("s_barrier" ::: "memory")
#define WAITV0() asm volatile("s_waitcnt vmcnt(0)" ::: "memory")
#define QSCALE 0.1803368801111137f   /* (1/8) * log2(e) */

__device__ inline u16 f2bf(float f) {
  union { float f; unsigned u; } v; v.f = f;
  unsigned r = v.u + 0x7fff + ((v.u >> 16) & 1);   // RNE
  return (u16)(r >> 16);
}

__device__ inline unsigned cvtpk(float lo, float hi_) {
  unsigned d;
  asm("v_cvt_pk_bf16_f32 %0, %1, %2" : "=v"(d) : "v"(lo), "v"(hi_));
  return d;
}

__device__ inline void perm32swap(unsigned& a, unsigned& b) {
  asm volatile("v_permlane32_swap_b32 %0, %1" : "+v"(a), "+v"(b));
}

__device__ inline void gload_lds16(const void* g, void* l) {
  __builtin_amdgcn_global_load_lds(
      (const __attribute__((address_space(1))) void*)g,
      (__attribute__((address_space(3))) void*)l, 16, 0, 0);
}

// ---------------- fp32 -> bf16 convert (vectorized) ----------------
__global__ void cvt_x_kernel(const float* __restrict__ x, u16* __restrict__ xb, int n4) {
  int i = blockIdx.x * 256 + threadIdx.x;
  if (i >= n4) return;
  float4 v = reinterpret_cast<const float4*>(x)[i];
  ushort4 o;
  o.x = f2bf(v.x); o.y = f2bf(v.y); o.z = f2bf(v.z); o.w = f2bf(v.w);
  reinterpret_cast<ushort4*>(xb)[i] = o;
}

// ---------------- all-weights transpose: W[K][N] fp32 -> Wt[N][K] bf16 ----------------
// z==0 (Wq) is PRE-SCALED by QSCALE so Q = X*Wq comes out softmax-scaled for free.
__global__ void transpose_w4_kernel(const float* __restrict__ wq, const float* __restrict__ wk,
                                    const float* __restrict__ wv, const float* __restrict__ wo,
                                    u16* __restrict__ wqkvT, u16* __restrict__ woT) {
  __shared__ float t[32][33];
  int z = blockIdx.z;
  const float* w = (z == 0) ? wq : (z == 1) ? wk : (z == 2) ? wv : wo;
  u16* wt = (z < 3) ? (wqkvT + (size_t)z * 1024 * 1024) : woT;
  const float sc = (z == 0) ? QSCALE : 1.0f;
  int tx = threadIdx.x, ty = threadIdx.y;
  int n0 = blockIdx.x * 32, k0 = blockIdx.y * 32;
#pragma unroll
  for (int j = 0; j < 32; j += 8)
    t[ty + j][tx] = w[(size_t)(k0 + ty + j) * D_DIM + n0 + tx];
  __syncthreads();
#pragma unroll
  for (int j = 0; j < 32; j += 8)
    wt[(size_t)(n0 + ty + j) * D_DIM + k0 + tx] = f2bf(t[tx][ty + j] * sc);
}

// ============ QKV GEMM: 128x128, single-buffer 2-sync (R6 body, VGPR 76) ============
__global__ __launch_bounds__(256) void gemm_qkv_kernel(
    const u16* __restrict__ A, const u16* __restrict__ Bt,
    u16* __restrict__ Qb, u16* __restrict__ KP, u16* __restrict__ VP) {
  __shared__ u16 lA[128 * 32];
  __shared__ u16 lB[128 * 32];
  const int tid = threadIdx.x, wid = tid >> 6, lane = tid & 63;
  const int bm = blockIdx.y, bn = blockIdx.x;
  const int fr = lane & 15, fq = lane >> 4;
  const int r0 = wid * 32;
  const int srow = lane >> 2, scol = (lane & 3) * 8;
  const u16* gA = A + (size_t)(bm * 128 + r0 + srow) * 1024 + scol;
  const u16* gB = Bt + (size_t)(bn * 128 + r0 + srow) * 1024 + scol;
  u16* lA0 = &lA[r0 * 32];
  u16* lB0 = &lB[r0 * 32];

  f32x4 acc[4][4] = {};
  const int wm = (wid >> 1) * 64, wn = (wid & 1) * 64;

  for (int k0 = 0; k0 < 1024; k0 += 32) {
    gload_lds16(gA + k0,             lA0);
    gload_lds16(gA + k0 + 16 * 1024, lA0 + 16 * 32);
    gload_lds16(gB + k0,             lB0);
    gload_lds16(gB + k0 + 16 * 1024, lB0 + 16 * 32);
    __syncthreads();
    bf16x8 fa[4], fb[4];
#pragma unroll
    for (int i = 0; i < 4; i++) {
      fa[i] = *(const bf16x8*)&lA[(wm + i * 16 + fr) * 32 + fq * 8];
      fb[i] = *(const bf16x8*)&lB[(wn + i * 16 + fr) * 32 + fq * 8];
    }
#pragma unroll
    for (int i = 0; i < 4; i++)
#pragma unroll
      for (int j = 0; j < 4; j++)
        acc[i][j] = __builtin_amdgcn_mfma_f32_16x16x32_bf16(fa[i], fb[j], acc[i][j], 0, 0, 0);
    __syncthreads();
  }

  const int col0 = bn * 128;   // wave-uniform region select
  if (col0 < 1024) {
#pragma unroll
    for (int i = 0; i < 4; i++)
#pragma unroll
      for (int j = 0; j < 4; j++)
#pragma unroll
        for (int r = 0; r < 4; r++) {
          int row = bm * 128 + wm + i * 16 + fq * 4 + r;
          int col = col0 + wn + j * 16 + fr;
          Qb[(size_t)row * 1024 + col] = f2bf(acc[i][j][r]);
        }
  } else if (col0 < 2048) {
#pragma unroll
    for (int i = 0; i < 4; i++)
#pragma unroll
      for (int j = 0; j < 4; j++) {
        int col = col0 + wn + j * 16 + fr;
        int ck = col - 1024;
        int h = ck >> 6, d = ck & 63;
        int sfr = d >> 4, e = d & 7, hb = (d >> 3) & 1;
#pragma unroll
        for (int r = 0; r < 4; r++) {
          int row = bm * 128 + wm + i * 16 + fq * 4 + r;
          int b = row >> 11, sp = row & 2047;
          int bh = b * 16 + h, jt = sp >> 5;
          int lanep = (sp & 31) + 32 * hb;
          KP[((size_t)(bh * 64 + jt) * 4 + sfr) * 512 + lanep * 8 + e] = f2bf(acc[i][j][r]);
        }
      }
  } else {
#pragma unroll
    for (int i = 0; i < 4; i++)
#pragma unroll
      for (int j = 0; j < 4; j++) {
        int col = col0 + wn + j * 16 + fr;
        int cv = col - 2048;
        int h = cv >> 6, d = cv & 63;
        int R0 = bm * 128 + wm + i * 16 + fq * 4;
        int b = R0 >> 11, sp0 = R0 & 2047;
        int bh = b * 16 + h, jt = sp0 >> 5;
        int c = (d >> 5) * 2 + ((sp0 >> 4) & 1);
        int lanep = (d & 31) + 32 * ((sp0 >> 3) & 1);
        int e0 = sp0 & 7;
        ushort4 ov;
        ov.x = f2bf(acc[i][j][0]); ov.y = f2bf(acc[i][j][1]);
        ov.z = f2bf(acc[i][j][2]); ov.w = f2bf(acc[i][j][3]);
        *(ushort4*)(VP + ((size_t)(bh * 64 + jt) * 4 + c) * 512 + lanep * 8 + e0) = ov;
      }
  }
}

// ============ out-proj GEMM: 128x128, dbuf one-barrier (R7-measured) ============
__global__ __launch_bounds__(256) void gemm_out_kernel(
    const u16* __restrict__ A, const u16* __restrict__ Bt,
    float* __restrict__ C, const float* __restrict__ bias) {
  __shared__ u16 lA[2][128 * 32];
  __shared__ u16 lB[2][128 * 32];
  const int tid = threadIdx.x, wid = tid >> 6, lane = tid & 63;
  const int bm = blockIdx.y, bn = blockIdx.x;
  const int fr = lane & 15, fq = lane >> 4;
  const int r0 = wid * 32;
  const int srow = lane >> 2, scol = (lane & 3) * 8;
  const u16* gA = A + (size_t)(bm * 128 + r0 + srow) * 1024 + scol;
  const u16* gB = Bt + (size_t)(bn * 128 + r0 + srow) * 1024 + scol;

  f32x4 acc[4][4] = {};
  const int wm = (wid >> 1) * 64, wn = (wid & 1) * 64;

  gload_lds16(gA,             &lA[0][r0 * 32]);
  gload_lds16(gA + 16 * 1024, &lA[0][r0 * 32 + 16 * 32]);
  gload_lds16(gB,             &lB[0][r0 * 32]);
  gload_lds16(gB + 16 * 1024, &lB[0][r0 * 32 + 16 * 32]);
  WAITV0();
  BAR();

#pragma unroll
  for (int k0 = 0; k0 < 1024; k0 += 32) {
    const int cur = (k0 >> 5) & 1, nxt = cur ^ 1;
    if (k0 + 32 < 1024) {
      gload_lds16(gA + k0 + 32,             &lA[nxt][r0 * 32]);
      gload_lds16(gA + k0 + 32 + 16 * 1024, &lA[nxt][r0 * 32 + 16 * 32]);
      gload_lds16(gB + k0 + 32,             &lB[nxt][r0 * 32]);
      gload_lds16(gB + k0 + 32 + 16 * 1024, &lB[nxt][r0 * 32 + 16 * 32]);
    }
    bf16x8 fa[4], fb[4];
#pragma unroll
    for (int i = 0; i < 4; i++) {
      fa[i] = *(const bf16x8*)&lA[cur][(wm + i * 16 + fr) * 32 + fq * 8];
      fb[i] = *(const bf16x8*)&lB[cur][(wn + i * 16 + fr) * 32 + fq * 8];
    }
#pragma unroll
    for (int i = 0; i < 4; i++)
#pragma unroll
      for (int j = 0; j < 4; j++)
        acc[i][j] = __builtin_amdgcn_mfma_f32_16x16x32_bf16(fa[i], fb[j], acc[i][j], 0, 0, 0);
    WAITV0();
    BAR();
  }

#pragma unroll
  for (int i = 0; i < 4; i++)
#pragma unroll
    for (int j = 0; j < 4; j++)
#pragma unroll
      for (int r = 0; r < 4; r++) {
        int row = bm * 128 + wm + i * 16 + fq * 4 + r;
        int col = bn * 128 + wn + j * 16 + fr;
        C[(size_t)row * 1024 + col] = acc[i][j][r] + bias[col];
      }
}

// ---------------- single-tile softmax+PV (tail) ----------------
__device__ __forceinline__ void sm_pv(f32x16& sa, float& m, float& l,
                                      f32x16& acc0, f32x16& acc1,
                                      bf16x8 vf00, bf16x8 vf01,
                                      bf16x8 vf10, bf16x8 vf11) {
  float x8[8], x4[4];
#pragma unroll
  for (int i = 0; i < 8; ++i) x8[i] = fmaxf(sa[2 * i], sa[2 * i + 1]);
#pragma unroll
  for (int i = 0; i < 4; ++i) x4[i] = fmaxf(x8[2 * i], x8[2 * i + 1]);
  float pm = fmaxf(fmaxf(x4[0], x4[1]), fmaxf(x4[2], x4[3]));
  pm = fmaxf(pm, __shfl_xor(pm, 32));

  if (__any(pm > m + 11.5f)) {
    float mn = fmaxf(m, pm);
    float sc = EXP2(m - mn);
    l *= sc;
#pragma unroll
    for (int r = 0; r < 16; ++r) { acc0[r] *= sc; acc1[r] *= sc; }
    m = mn;
  }

  float rs = 0.f;
#pragma unroll
  for (int r = 0; r < 16; ++r) { sa[r] = EXP2(sa[r] - m); rs += sa[r]; }
  rs += __shfl_xor(rs, 32);
  l += rs;

  unsigned c0 = cvtpk(sa[0],  sa[1]),  c1 = cvtpk(sa[2],  sa[3]);
  unsigned c2 = cvtpk(sa[4],  sa[5]),  c3 = cvtpk(sa[6],  sa[7]);
  unsigned c4 = cvtpk(sa[8],  sa[9]),  c5 = cvtpk(sa[10], sa[11]);
  unsigned c6 = cvtpk(sa[12], sa[13]), c7 = cvtpk(sa[14], sa[15]);
  perm32swap(c0, c2); perm32swap(c1, c3);
  perm32swap(c4, c6); perm32swap(c5, c7);
  union U4 { unsigned u[4]; bf16x8 v; } F0, F1;
  F0.u[0] = c0; F0.u[1] = c1; F0.u[2] = c2; F0.u[3] = c3;
  F1.u[0] = c4; F1.u[1] = c5; F1.u[2] = c6; F1.u[3] = c7;

  __builtin_amdgcn_s_setprio(1);
  acc0 = __builtin_amdgcn_mfma_f32_32x32x16_bf16(vf00, F0.v, acc0, 0, 0, 0);
  acc0 = __builtin_amdgcn_mfma_f32_32x32x16_bf16(vf01, F1.v, acc0, 0, 0, 0);
  acc1 = __builtin_amdgcn_mfma_f32_32x32x16_bf16(vf10, F0.v, acc1, 0, 0, 0);
  acc1 = __builtin_amdgcn_mfma_f32_32x32x16_bf16(vf11, F1.v, acc1, 0, 0, 0);
  __builtin_amdgcn_s_setprio(0);
}

__device__ __forceinline__ void attn_store(u16* Orow, const f32x16& a0,
                                           const f32x16& a1, float inv, int hi) {
#pragma unroll
  for (int g = 0; g < 4; ++g) {
    ushort4 o4;
    o4.x = f2bf(a0[g * 4 + 0] * inv); o4.y = f2bf(a0[g * 4 + 1] * inv);
    o4.z = f2bf(a0[g * 4 + 2] * inv); o4.w = f2bf(a0[g * 4 + 3] * inv);
    *(ushort4*)(Orow + 8 * g + 4 * hi) = o4;
  }
#pragma unroll
  for (int g = 0; g < 4; ++g) {
    ushort4 o4;
    o4.x = f2bf(a1[g * 4 + 0] * inv); o4.y = f2bf(a1[g * 4 + 1] * inv);
    o4.z = f2bf(a1[g * 4 + 2] * inv); o4.w = f2bf(a1[g * 4 + 3] * inv);
    *(ushort4*)(Orow + 32 + 8 * g + 4 * hi) = o4;
  }
}

// 2-tile (64-key) step: two independent QK chains, ONE joint softmax, 8 PV MFMAs.
// vf loads placed after QK so softmax covers their L2 latency.
#define PAIR_STEP(T, MB) {                                                      \
  const size_t fbA = (size_t)(T) * 256 + lane;                                  \
  bf16x8 kA0 = KPt[fbA],       kA1 = KPt[fbA + 64],                             \
         kA2 = KPt[fbA + 128], kA3 = KPt[fbA + 192];                            \
  bf16x8 kB0 = KPt[fbA + 256], kB1 = KPt[fbA + 320],                            \
         kB2 = KPt[fbA + 384], kB3 = KPt[fbA + 448];                            \
  f32x16 saA = {}, saB = {};                                                    \
  __builtin_amdgcn_s_setprio(1);                                                \
  saA = __builtin_amdgcn_mfma_f32_32x32x16_bf16(kA0, qf[0], saA, 0, 0, 0);      \
  saB = __builtin_amdgcn_mfma_f32_32x32x16_bf16(kB0, qf[0], saB, 0, 0, 0);      \
  saA = __builtin_amdgcn_mfma_f32_32x32x16_bf16(kA1, qf[1], saA, 0, 0, 0);      \
  saB = __builtin_amdgcn_mfma_f32_32x32x16_bf16(kB1, qf[1], saB, 0, 0, 0);      \
  saA = __builtin_amdgcn_mfma_f32_32x32x16_bf16(kA2, qf[2], saA, 0, 0, 0);      \
  saB = __builtin_amdgcn_mfma_f32_32x32x16_bf16(kB2, qf[2], saB, 0, 0, 0);      \
  saA = __builtin_amdgcn_mfma_f32_32x32x16_bf16(kA3, qf[3], saA, 0, 0, 0);      \
  saB = __builtin_amdgcn_mfma_f32_32x32x16_bf16(kB3, qf[3], saB, 0, 0, 0);      \
  __builtin_amdgcn_s_setprio(0);                                                \
  bf16x8 vA00 = VPt[fbA],       vA01 = VPt[fbA + 64],                           \
         vA10 = VPt[fbA + 128], vA11 = VPt[fbA + 192];                          \
  bf16x8 vB00 = VPt[fbA + 256], vB01 = VPt[fbA + 320],                          \
         vB10 = VPt[fbA + 384], vB11 = VPt[fbA + 448];                          \
  if (MB) {                                                                     \
    const int j0m = ((T) + 1) * 32;                                             \
    _Pragma("unroll") for (int r = 0; r < 16; ++r) {                            \
      int kidx = j0m + (r & 3) + 8 * (r >> 2) + 4 * hi;                         \
      if (kidx > q) saB[r] = -3.0e38f;                                          \
    }                                                                           \
  }                                                                             \
  float x16[16], x8s[8], x4s[4];                                                \
  _Pragma("unroll") for (int i = 0; i < 8; ++i) {                               \
    x16[i]     = fmaxf(saA[2 * i], saA[2 * i + 1]);                             \
    x16[8 + i] = fmaxf(saB[2 * i], saB[2 * i + 1]);                             \
  }                                                                             \
  _Pragma("unroll") for (int i = 0; i < 8; ++i)                                 \
    x8s[i] = fmaxf(x16[2 * i], x16[2 * i + 1]);                                 \
  _Pragma("unroll") for (int i = 0; i < 4; ++i)                                 \
    x4s[i] = fmaxf(x8s[2 * i], x8s[2 * i + 1]);                                 \
  float pm = fmaxf(fmaxf(x4s[0], x4s[1]), fmaxf(x4s[2], x4s[3]));               \
  pm = fmaxf(pm, __shfl_xor(pm, 32));                                           \
  if (__any(pm > m + 11.5f)) {                                                  \
    float mn = fmaxf(m, pm);                                                    \
    float sc = EXP2(m - mn);                                                    \
    l *= sc;                                                                    \
    _Pragma("unroll") for (int r = 0; r < 16; ++r) { acc0[r] *= sc; acc1[r] *= sc; } \
    m = mn;                                                                     \
  }                                                                             \
  float rs = 0.f;                                                               \
  _Pragma("unroll") for (int r = 0; r < 16; ++r) {                              \
    saA[r] = EXP2(saA[r] - m); rs += saA[r];                                    \
    saB[r] = EXP2(saB[r] - m); rs += saB[r];                                    \
  }                                                                             \
  rs += __shfl_xor(rs, 32);                                                     \
  l += rs;                                                                      \
  unsigned a0 = cvtpk(saA[0], saA[1]),   a1 = cvtpk(saA[2], saA[3]);            \
  unsigned a2 = cvtpk(saA[4], saA[5]),   a3 = cvtpk(saA[6], saA[7]);            \
  unsigned a4 = cvtpk(saA[8], saA[9]),   a5 = cvtpk(saA[10], saA[11]);          \
  unsigned a6 = cvtpk(saA[12], saA[13]), a7 = cvtpk(saA[14], saA[15]);          \
  perm32swap(a0, a2); perm32swap(a1, a3); perm32swap(a4, a6); perm32swap(a5, a7); \
  unsigned b0 = cvtpk(saB[0], saB[1]),   b1 = cvtpk(saB[2], saB[3]);            \
  unsigned b2 = cvtpk(saB[4], saB[5]),   b3 = cvtpk(saB[6], saB[7]);            \
  unsigned b4 = cvtpk(saB[8], saB[9]),   b5 = cvtpk(saB[10], saB[11]);          \
  unsigned b6 = cvtpk(saB[12], saB[13]), b7 = cvtpk(saB[14], saB[15]);          \
  perm32swap(b0, b2); perm32swap(b1, b3); perm32swap(b4, b6); perm32swap(b5, b7); \
  union U4 { unsigned u[4]; bf16x8 v; } FA0, FA1, FB0, FB1;                     \
  FA0.u[0] = a0; FA0.u[1] = a1; FA0.u[2] = a2; FA0.u[3] = a3;                   \
  FA1.u[0] = a4; FA1.u[1] = a5; FA1.u[2] = a6; FA1.u[3] = a7;                   \
  FB0.u[0] = b0; FB0.u[1] = b1; FB0.u[2] = b2; FB0.u[3] = b3;                   \
  FB1.u[0] = b4; FB1.u[1] = b5; FB1.u[2] = b6; FB1.u[3] = b7;                   \
  __builtin_amdgcn_s_setprio(1);                                                \
  acc0 = __builtin_amdgcn_mfma_f32_32x32x16_bf16(vA00, FA0.v, acc0, 0, 0, 0);   \
  acc1 = __builtin_amdgcn_mfma_f32_32x32x16_bf16(vA10, FA0.v, acc1, 0, 0, 0);   \
  acc0 = __builtin_amdgcn_mfma_f32_32x32x16_bf16(vA01, FA1.v, acc0, 0, 0, 0);   \
  acc1 = __builtin_amdgcn_mfma_f32_32x32x16_bf16(vA11, FA1.v, acc1, 0, 0, 0);   \
  acc0 = __builtin_amdgcn_mfma_f32_32x32x16_bf16(vB00, FB0.v, acc0, 0, 0, 0);   \
  acc1 = __builtin_amdgcn_mfma_f32_32x32x16_bf16(vB10, FB0.v, acc1, 0, 0, 0);   \
  acc0 = __builtin_amdgcn_mfma_f32_32x32x16_bf16(vB01, FB1.v, acc0, 0, 0, 0);   \
  acc1 = __builtin_amdgcn_mfma_f32_32x32x16_bf16(vB11, FB1.v, acc1, 0, 0, 0);   \
  __builtin_amdgcn_s_setprio(0);                                                \
}

// ---------------- flash attention (causal), 64-key double-tile ILP ----------------
// R10 grid: 1024 blocks (full TLP), wave owns 32 q rows; 2 KV tiles per iteration.
__global__ __launch_bounds__(256) void attn_kernel(
    const u16* __restrict__ Q, const u16* __restrict__ KP,
    const u16* __restrict__ VP, u16* __restrict__ O) {
  const int tid = threadIdx.x, wid = tid >> 6, lane = tid & 63;
  const int lq = lane & 31, hi = lane >> 5;
  int f = blockIdx.x;
  int xcd = f & 7, kk = f >> 3;
  int bh = xcd * 8 + (kk & 7);
  int qblk = 15 - (kk >> 3);      // big tiles dispatched first
  int b = bh >> 4, h = bh & 15;
  int q0 = qblk * 128 + wid * 32;
  int q = q0 + lq;

  const u16* Qrow = Q + (size_t)(b * S_LEN + q) * D_DIM + h * HDIM;
  bf16x8 qf[4];
#pragma unroll
  for (int s = 0; s < 4; s++)
    qf[s] = *(const bf16x8*)(Qrow + s * 16 + hi * 8);

  const bf16x8* KPt = (const bf16x8*)KP + (size_t)bh * 64 * 4 * 64;
  const bf16x8* VPt = (const bf16x8*)VP + (size_t)bh * 64 * 4 * 64;

  f32x16 acc0 = {}, acc1 = {};
  float m = -3.0e38f, l = 0.f;
  const int nt = qblk * 4 + wid + 1;

  int t = 0;
  for (; t + 2 < nt; t += 2)
    PAIR_STEP(t, false);

  if (t + 2 == nt) {
    PAIR_STEP(t, true);           // diagonal in tile B
  } else {
    // single masked tile t == nt-1
    const int j0 = t * 32;
    const size_t fb = (size_t)t * 256 + lane;
    bf16x8 kf0 = KPt[fb], kf1 = KPt[fb + 64], kf2 = KPt[fb + 128], kf3 = KPt[fb + 192];
    bf16x8 vf00 = VPt[fb], vf01 = VPt[fb + 64], vf10 = VPt[fb + 128], vf11 = VPt[fb + 192];
    f32x16 sa = {};
    __builtin_amdgcn_s_setprio(1);
    sa = __builtin_amdgcn_mfma_f32_32x32x16_bf16(kf0, qf[0], sa, 0, 0, 0);
    sa = __builtin_amdgcn_mfma_f32_32x32x16_bf16(kf1, qf[1], sa, 0, 0, 0);
    sa = __builtin_amdgcn_mfma_f32_32x32x16_bf16(kf2, qf[2], sa, 0, 0, 0);
    sa = __builtin_amdgcn_mfma_f32_32x32x16_bf16(kf3, qf[3], sa, 0, 0, 0);
    __builtin_amdgcn_s_setprio(0);
#pragma unroll
    for (int r = 0; r < 16; ++r) {
      int kidx = j0 + (r & 3) + 8 * (r >> 2) + 4 * hi;
      if (kidx > q) sa[r] = -3.0e38f;
    }
    sm_pv(sa, m, l, acc0, acc1, vf00, vf01, vf10, vf11);
  }

  attn_store(O + (size_t)(b * S_LEN + q) * D_DIM + h * HDIM, acc0, acc1, 1.f / l, hi);
}

// ---------------- launcher ----------------
extern "C" void kernel_launch(void* const* d_in, const int* in_sizes, int n_in,
                              void* d_out, int out_size, void* d_ws, size_t ws_size,
                              hipStream_t stream) {
  const float* x  = (const float*)d_in[0];
  const float* wq = (const float*)d_in[1];
  const float* wk = (const float*)d_in[2];
  const float* wv = (const float*)d_in[3];
  const float* wo = (const float*)d_in[4];
  const float* ob = (const float*)d_in[5];
  float* out = (float*)d_out;

  char* ws = (char*)d_ws;
  u16* Xb    = (u16*)(ws);                              // slot A: Xb then Ab
  u16* Ab    = (u16*)(ws);
  u16* Qb    = (u16*)(ws + (size_t)16 * 1024 * 1024);   // 16 MB
  u16* KPb   = (u16*)(ws + (size_t)32 * 1024 * 1024);   // 16 MB
  u16* VPb   = (u16*)(ws + (size_t)48 * 1024 * 1024);   // 16 MB
  u16* WqkvT = (u16*)(ws + (size_t)64 * 1024 * 1024);   // 6 MB
  u16* WoT   = (u16*)(ws + (size_t)70 * 1024 * 1024);   // 2 MB

  cvt_x_kernel<<<(MROWS * D_DIM / 4) / 256, 256, 0, stream>>>(x, Xb, MROWS * D_DIM / 4);

  transpose_w4_kernel<<<dim3(32, 32, 4), dim3(32, 8), 0, stream>>>(
      wq, wk, wv, wo, WqkvT, WoT);

  // fused QKV projection [8192,1024]x[1024,3072] with fused Q/K/V pack epilogue
  gemm_qkv_kernel<<<dim3(24, 64), 256, 0, stream>>>(Xb, WqkvT, Qb, KPb, VPb);

  attn_kernel<<<dim3(1024), 256, 0, stream>>>(Qb, KPb, VPb, Ab);

  // out projection [8192,1024]x[1024,1024] + bias, fp32 out
  gemm_out_kernel<<<dim3(8, 64), 256, 0, stream>>>(Ab, WoT, out, ob);
}

// Round 13
// 174.122 us; speedup vs baseline: 1.1652x; 1.0388x over previous
//
#include <hip/hip_runtime.h>
#include <hip/hip_bf16.h>

#define S_LEN 2048
#define D_DIM 1024
#define NHEAD 16
#define HDIM  64
#define BATCH 4
#define MROWS (BATCH*S_LEN)   /* 8192 */

typedef short bf16x8 __attribute__((ext_vector_type(8)));
typedef float f32x4  __attribute__((ext_vector_type(4)));
typedef float f32x16 __attribute__((ext_vector_type(16)));
typedef unsigned short u16;

#if __has_builtin(__builtin_amdgcn_exp2f)
#define EXP2(x) __builtin_amdgcn_exp2f(x)
#else
#define EXP2(x) __expf((x) * 0.6931471805599453f)
#endif

#define BAR() asm volatile("s_barrier" ::: "memory")
#define WAITV0() asm volatile("s_waitcnt vmcnt(0)" ::: "memory")
#define QSCALE 0.1803368801111137f   /* (1/8) * log2(e) */

__device__ inline u16 f2bf(float f) {
  union { float f; unsigned u; } v; v.f = f;
  unsigned r = v.u + 0x7fff + ((v.u >> 16) & 1);   // RNE
  return (u16)(r >> 16);
}

__device__ inline unsigned cvtpk(float lo, float hi_) {
  unsigned d;
  asm("v_cvt_pk_bf16_f32 %0, %1, %2" : "=v"(d) : "v"(lo), "v"(hi_));
  return d;
}

__device__ inline void perm32swap(unsigned& a, unsigned& b) {
  asm volatile("v_permlane32_swap_b32 %0, %1" : "+v"(a), "+v"(b));
}

__device__ inline void gload_lds16(const void* g, void* l) {
  __builtin_amdgcn_global_load_lds(
      (const __attribute__((address_space(1))) void*)g,
      (__attribute__((address_space(3))) void*)l, 16, 0, 0);
}

// ---------------- fused prep: X fp32->bf16 + 4 weight transposes ----------------
// blocks [0,8192): convert X (float4/thread). blocks [8192,12288): transpose weights.
// Wq (z==0) pre-scaled by QSCALE.
__global__ __launch_bounds__(256) void prep_kernel(
    const float* __restrict__ x, u16* __restrict__ xb,
    const float* __restrict__ wq, const float* __restrict__ wk,
    const float* __restrict__ wv, const float* __restrict__ wo,
    u16* __restrict__ wqkvT, u16* __restrict__ woT) {
  __shared__ float t[32][33];
  const int bid = blockIdx.x, tid = threadIdx.x;
  if (bid < 8192) {
    int i = bid * 256 + tid;
    float4 v = reinterpret_cast<const float4*>(x)[i];
    ushort4 o;
    o.x = f2bf(v.x); o.y = f2bf(v.y); o.z = f2bf(v.z); o.w = f2bf(v.w);
    reinterpret_cast<ushort4*>(xb)[i] = o;
    return;
  }
  const int wb = bid - 8192;        // [0,4096)
  const int z = wb >> 10;           // weight id
  const int rem = wb & 1023;
  const int bx = rem & 31, by = rem >> 5;
  const float* w = (z == 0) ? wq : (z == 1) ? wk : (z == 2) ? wv : wo;
  u16* wt = (z < 3) ? (wqkvT + (size_t)z * 1024 * 1024) : woT;
  const float sc = (z == 0) ? QSCALE : 1.0f;
  const int tx = tid & 31, ty = tid >> 5;   // (32,8)
  const int n0 = bx * 32, k0 = by * 32;
#pragma unroll
  for (int j = 0; j < 32; j += 8)
    t[ty + j][tx] = w[(size_t)(k0 + ty + j) * D_DIM + n0 + tx];
  __syncthreads();
#pragma unroll
  for (int j = 0; j < 32; j += 8)
    wt[(size_t)(n0 + ty + j) * D_DIM + k0 + tx] = f2bf(t[tx][ty + j] * sc);
}

// ============ QKV GEMM: 128x128, single-buffer 2-sync (R6 body, VGPR 76) ============
// 1D grid 1536 with XCD-chunk swizzle: each XCD owns 8 contiguous bm-panels (bn fastest).
__global__ __launch_bounds__(256) void gemm_qkv_kernel(
    const u16* __restrict__ A, const u16* __restrict__ Bt,
    u16* __restrict__ Qb, u16* __restrict__ KP, u16* __restrict__ VP) {
  __shared__ u16 lA[128 * 32];
  __shared__ u16 lB[128 * 32];
  const int tid = threadIdx.x, wid = tid >> 6, lane = tid & 63;
  const int wg = blockIdx.x;                       // [0,1536)
  const int swz = (wg & 7) * 192 + (wg >> 3);      // XCD-chunk (1536 % 8 == 0)
  const int bm = swz / 24, bn = swz % 24;
  const int fr = lane & 15, fq = lane >> 4;
  const int r0 = wid * 32;
  const int srow = lane >> 2, scol = (lane & 3) * 8;
  const u16* gA = A + (size_t)(bm * 128 + r0 + srow) * 1024 + scol;
  const u16* gB = Bt + (size_t)(bn * 128 + r0 + srow) * 1024 + scol;
  u16* lA0 = &lA[r0 * 32];
  u16* lB0 = &lB[r0 * 32];

  f32x4 acc[4][4] = {};
  const int wm = (wid >> 1) * 64, wn = (wid & 1) * 64;

  for (int k0 = 0; k0 < 1024; k0 += 32) {
    gload_lds16(gA + k0,             lA0);
    gload_lds16(gA + k0 + 16 * 1024, lA0 + 16 * 32);
    gload_lds16(gB + k0,             lB0);
    gload_lds16(gB + k0 + 16 * 1024, lB0 + 16 * 32);
    __syncthreads();
    bf16x8 fa[4], fb[4];
#pragma unroll
    for (int i = 0; i < 4; i++) {
      fa[i] = *(const bf16x8*)&lA[(wm + i * 16 + fr) * 32 + fq * 8];
      fb[i] = *(const bf16x8*)&lB[(wn + i * 16 + fr) * 32 + fq * 8];
    }
#pragma unroll
    for (int i = 0; i < 4; i++)
#pragma unroll
      for (int j = 0; j < 4; j++)
        acc[i][j] = __builtin_amdgcn_mfma_f32_16x16x32_bf16(fa[i], fb[j], acc[i][j], 0, 0, 0);
    __syncthreads();
  }

  const int col0 = bn * 128;   // wave-uniform region select
  if (col0 < 1024) {
#pragma unroll
    for (int i = 0; i < 4; i++)
#pragma unroll
      for (int j = 0; j < 4; j++)
#pragma unroll
        for (int r = 0; r < 4; r++) {
          int row = bm * 128 + wm + i * 16 + fq * 4 + r;
          int col = col0 + wn + j * 16 + fr;
          Qb[(size_t)row * 1024 + col] = f2bf(acc[i][j][r]);
        }
  } else if (col0 < 2048) {
#pragma unroll
    for (int i = 0; i < 4; i++)
#pragma unroll
      for (int j = 0; j < 4; j++) {
        int col = col0 + wn + j * 16 + fr;
        int ck = col - 1024;
        int h = ck >> 6, d = ck & 63;
        int sfr = d >> 4, e = d & 7, hb = (d >> 3) & 1;
#pragma unroll
        for (int r = 0; r < 4; r++) {
          int row = bm * 128 + wm + i * 16 + fq * 4 + r;
          int b = row >> 11, sp = row & 2047;
          int bh = b * 16 + h, jt = sp >> 5;
          int lanep = (sp & 31) + 32 * hb;
          KP[((size_t)(bh * 64 + jt) * 4 + sfr) * 512 + lanep * 8 + e] = f2bf(acc[i][j][r]);
        }
      }
  } else {
#pragma unroll
    for (int i = 0; i < 4; i++)
#pragma unroll
      for (int j = 0; j < 4; j++) {
        int col = col0 + wn + j * 16 + fr;
        int cv = col - 2048;
        int h = cv >> 6, d = cv & 63;
        int R0 = bm * 128 + wm + i * 16 + fq * 4;
        int b = R0 >> 11, sp0 = R0 & 2047;
        int bh = b * 16 + h, jt = sp0 >> 5;
        int c = (d >> 5) * 2 + ((sp0 >> 4) & 1);
        int lanep = (d & 31) + 32 * ((sp0 >> 3) & 1);
        int e0 = sp0 & 7;
        ushort4 ov;
        ov.x = f2bf(acc[i][j][0]); ov.y = f2bf(acc[i][j][1]);
        ov.z = f2bf(acc[i][j][2]); ov.w = f2bf(acc[i][j][3]);
        *(ushort4*)(VP + ((size_t)(bh * 64 + jt) * 4 + c) * 512 + lanep * 8 + e0) = ov;
      }
  }
}

// ============ out-proj GEMM: 128x128, dbuf one-barrier (R7-measured) ============
__global__ __launch_bounds__(256) void gemm_out_kernel(
    const u16* __restrict__ A, const u16* __restrict__ Bt,
    float* __restrict__ C, const float* __restrict__ bias) {
  __shared__ u16 lA[2][128 * 32];
  __shared__ u16 lB[2][128 * 32];
  const int tid = threadIdx.x, wid = tid >> 6, lane = tid & 63;
  const int bm = blockIdx.y, bn = blockIdx.x;
  const int fr = lane & 15, fq = lane >> 4;
  const int r0 = wid * 32;
  const int srow = lane >> 2, scol = (lane & 3) * 8;
  const u16* gA = A + (size_t)(bm * 128 + r0 + srow) * 1024 + scol;
  const u16* gB = Bt + (size_t)(bn * 128 + r0 + srow) * 1024 + scol;

  f32x4 acc[4][4] = {};
  const int wm = (wid >> 1) * 64, wn = (wid & 1) * 64;

  gload_lds16(gA,             &lA[0][r0 * 32]);
  gload_lds16(gA + 16 * 1024, &lA[0][r0 * 32 + 16 * 32]);
  gload_lds16(gB,             &lB[0][r0 * 32]);
  gload_lds16(gB + 16 * 1024, &lB[0][r0 * 32 + 16 * 32]);
  WAITV0();
  BAR();

#pragma unroll
  for (int k0 = 0; k0 < 1024; k0 += 32) {
    const int cur = (k0 >> 5) & 1, nxt = cur ^ 1;
    if (k0 + 32 < 1024) {
      gload_lds16(gA + k0 + 32,             &lA[nxt][r0 * 32]);
      gload_lds16(gA + k0 + 32 + 16 * 1024, &lA[nxt][r0 * 32 + 16 * 32]);
      gload_lds16(gB + k0 + 32,             &lB[nxt][r0 * 32]);
      gload_lds16(gB + k0 + 32 + 16 * 1024, &lB[nxt][r0 * 32 + 16 * 32]);
    }
    bf16x8 fa[4], fb[4];
#pragma unroll
    for (int i = 0; i < 4; i++) {
      fa[i] = *(const bf16x8*)&lA[cur][(wm + i * 16 + fr) * 32 + fq * 8];
      fb[i] = *(const bf16x8*)&lB[cur][(wn + i * 16 + fr) * 32 + fq * 8];
    }
#pragma unroll
    for (int i = 0; i < 4; i++)
#pragma unroll
      for (int j = 0; j < 4; j++)
        acc[i][j] = __builtin_amdgcn_mfma_f32_16x16x32_bf16(fa[i], fb[j], acc[i][j], 0, 0, 0);
    WAITV0();
    BAR();
  }

#pragma unroll
  for (int i = 0; i < 4; i++)
#pragma unroll
    for (int j = 0; j < 4; j++)
#pragma unroll
      for (int r = 0; r < 4; r++) {
        int row = bm * 128 + wm + i * 16 + fq * 4 + r;
        int col = bn * 128 + wn + j * 16 + fr;
        C[(size_t)row * 1024 + col] = acc[i][j][r] + bias[col];
      }
}

// ---------------- flash attention (causal), swapped-operand 32x32 MFMA (R10) ----------------
// Q is pre-scaled by (1/8)*log2(e) via Wq: MFMA output is directly log2-domain scores.
__global__ __launch_bounds__(256) void attn_kernel(
    const u16* __restrict__ Q, const u16* __restrict__ KP,
    const u16* __restrict__ VP, u16* __restrict__ O) {
  const int tid = threadIdx.x, wid = tid >> 6, lane = tid & 63;
  const int lq = lane & 31, hi = lane >> 5;
  int f = blockIdx.x;
  int xcd = f & 7, kk = f >> 3;
  int bh = xcd * 8 + (kk & 7);
  int qblk = 15 - (kk >> 3);
  int b = bh >> 4, h = bh & 15;
  int q0 = qblk * 128 + wid * 32;
  int q = q0 + lq;

  const u16* Qrow = Q + (size_t)(b * S_LEN + q) * D_DIM + h * HDIM;
  bf16x8 qf[4];
#pragma unroll
  for (int s = 0; s < 4; s++)
    qf[s] = *(const bf16x8*)(Qrow + s * 16 + hi * 8);

  const bf16x8* KPt = (const bf16x8*)KP + (size_t)bh * 64 * 4 * 64;
  const bf16x8* VPt = (const bf16x8*)VP + (size_t)bh * 64 * 4 * 64;

  f32x16 acc0 = {}, acc1 = {};
  float m = -3.0e38f, l = 0.f;
  const int nt = qblk * 4 + wid + 1;

  for (int t = 0; t < nt; ++t) {
    const int j0 = t * 32;
    const size_t fb = (size_t)t * 4 * 64 + lane;
    bf16x8 kf0 = KPt[fb], kf1 = KPt[fb + 64], kf2 = KPt[fb + 128], kf3 = KPt[fb + 192];
    bf16x8 vf00 = VPt[fb], vf01 = VPt[fb + 64], vf10 = VPt[fb + 128], vf11 = VPt[fb + 192];

    f32x16 sa = {};
    __builtin_amdgcn_s_setprio(1);
    sa = __builtin_amdgcn_mfma_f32_32x32x16_bf16(kf0, qf[0], sa, 0, 0, 0);
    sa = __builtin_amdgcn_mfma_f32_32x32x16_bf16(kf1, qf[1], sa, 0, 0, 0);
    sa = __builtin_amdgcn_mfma_f32_32x32x16_bf16(kf2, qf[2], sa, 0, 0, 0);
    sa = __builtin_amdgcn_mfma_f32_32x32x16_bf16(kf3, qf[3], sa, 0, 0, 0);
    __builtin_amdgcn_s_setprio(0);

    float p[16];
#pragma unroll
    for (int r = 0; r < 16; ++r) p[r] = sa[r];

    if (t == nt - 1) {
#pragma unroll
      for (int r = 0; r < 16; ++r) {
        int kidx = j0 + (r & 3) + 8 * (r >> 2) + 4 * hi;
        if (kidx > q) p[r] = -3.0e38f;
      }
    }

    float x8[8], x4[4], x2[2];
#pragma unroll
    for (int i = 0; i < 8; ++i) x8[i] = fmaxf(p[2 * i], p[2 * i + 1]);
#pragma unroll
    for (int i = 0; i < 4; ++i) x4[i] = fmaxf(x8[2 * i], x8[2 * i + 1]);
    x2[0] = fmaxf(x4[0], x4[1]); x2[1] = fmaxf(x4[2], x4[3]);
    float pm = fmaxf(x2[0], x2[1]);
    pm = fmaxf(pm, __shfl_xor(pm, 32));

    if (__any(pm > m + 11.5f)) {
      float mn = fmaxf(m, pm);
      float sc = EXP2(m - mn);
      l *= sc;
#pragma unroll
      for (int r = 0; r < 16; ++r) { acc0[r] *= sc; acc1[r] *= sc; }
      m = mn;
    }

    float rs = 0.f;
#pragma unroll
    for (int r = 0; r < 16; ++r) { p[r] = EXP2(p[r] - m); rs += p[r]; }
    rs += __shfl_xor(rs, 32);
    l += rs;

    unsigned c0 = cvtpk(p[0],  p[1]),  c1 = cvtpk(p[2],  p[3]);
    unsigned c2 = cvtpk(p[4],  p[5]),  c3 = cvtpk(p[6],  p[7]);
    unsigned c4 = cvtpk(p[8],  p[9]),  c5 = cvtpk(p[10], p[11]);
    unsigned c6 = cvtpk(p[12], p[13]), c7 = cvtpk(p[14], p[15]);
    perm32swap(c0, c2); perm32swap(c1, c3);
    perm32swap(c4, c6); perm32swap(c5, c7);
    union U4 { unsigned u[4]; bf16x8 v; } F0, F1;
    F0.u[0] = c0; F0.u[1] = c1; F0.u[2] = c2; F0.u[3] = c3;
    F1.u[0] = c4; F1.u[1] = c5; F1.u[2] = c6; F1.u[3] = c7;

    __builtin_amdgcn_s_setprio(1);
    acc0 = __builtin_amdgcn_mfma_f32_32x32x16_bf16(vf00, F0.v, acc0, 0, 0, 0);
    acc0 = __builtin_amdgcn_mfma_f32_32x32x16_bf16(vf01, F1.v, acc0, 0, 0, 0);
    acc1 = __builtin_amdgcn_mfma_f32_32x32x16_bf16(vf10, F0.v, acc1, 0, 0, 0);
    acc1 = __builtin_amdgcn_mfma_f32_32x32x16_bf16(vf11, F1.v, acc1, 0, 0, 0);
    __builtin_amdgcn_s_setprio(0);
  }

  float inv = 1.f / l;
  u16* Orow = O + (size_t)(b * S_LEN + q) * D_DIM + h * HDIM;
#pragma unroll
  for (int g = 0; g < 4; ++g) {
    ushort4 o4;
    o4.x = f2bf(acc0[g * 4 + 0] * inv);
    o4.y = f2bf(acc0[g * 4 + 1] * inv);
    o4.z = f2bf(acc0[g * 4 + 2] * inv);
    o4.w = f2bf(acc0[g * 4 + 3] * inv);
    *(ushort4*)(Orow + 8 * g + 4 * hi) = o4;
  }
#pragma unroll
  for (int g = 0; g < 4; ++g) {
    ushort4 o4;
    o4.x = f2bf(acc1[g * 4 + 0] * inv);
    o4.y = f2bf(acc1[g * 4 + 1] * inv);
    o4.z = f2bf(acc1[g * 4 + 2] * inv);
    o4.w = f2bf(acc1[g * 4 + 3] * inv);
    *(ushort4*)(Orow + 32 + 8 * g + 4 * hi) = o4;
  }
}

// ---------------- launcher ----------------
extern "C" void kernel_launch(void* const* d_in, const int* in_sizes, int n_in,
                              void* d_out, int out_size, void* d_ws, size_t ws_size,
                              hipStream_t stream) {
  const float* x  = (const float*)d_in[0];
  const float* wq = (const float*)d_in[1];
  const float* wk = (const float*)d_in[2];
  const float* wv = (const float*)d_in[3];
  const float* wo = (const float*)d_in[4];
  const float* ob = (const float*)d_in[5];
  float* out = (float*)d_out;

  char* ws = (char*)d_ws;
  u16* Xb    = (u16*)(ws);                              // slot A: Xb then Ab
  u16* Ab    = (u16*)(ws);
  u16* Qb    = (u16*)(ws + (size_t)16 * 1024 * 1024);   // 16 MB
  u16* KPb   = (u16*)(ws + (size_t)32 * 1024 * 1024);   // 16 MB
  u16* VPb   = (u16*)(ws + (size_t)48 * 1024 * 1024);   // 16 MB
  u16* WqkvT = (u16*)(ws + (size_t)64 * 1024 * 1024);   // 6 MB
  u16* WoT   = (u16*)(ws + (size_t)70 * 1024 * 1024);   // 2 MB

  // fused prep: X convert (8192 blocks) + 4 weight transposes (4096 blocks)
  prep_kernel<<<dim3(12288), 256, 0, stream>>>(x, Xb, wq, wk, wv, wo, WqkvT, WoT);

  // fused QKV projection [8192,1024]x[1024,3072] with fused Q/K/V pack epilogue
  gemm_qkv_kernel<<<dim3(1536), 256, 0, stream>>>(Xb, WqkvT, Qb, KPb, VPb);

  attn_kernel<<<dim3(1024), 256, 0, stream>>>(Qb, KPb, VPb, Ab);

  // out projection [8192,1024]x[1024,1024] + bias, fp32 out
  gemm_out_kernel<<<dim3(8, 64), 256, 0, stream>>>(Ab, WoT, out, ob);
}

// Round 14
// 168.189 us; speedup vs baseline: 1.2063x; 1.0353x over previous
//
#include <hip/hip_runtime.h>
#include <hip/hip_bf16.h>

#define S_LEN 2048
#define D_DIM 1024
#define NHEAD 16
#define HDIM  64
#define BATCH 4
#define MROWS (BATCH*S_LEN)   /* 8192 */

typedef short bf16x8 __attribute__((ext_vector_type(8)));
typedef float f32x4  __attribute__((ext_vector_type(4)));
typedef float f32x16 __attribute__((ext_vector_type(16)));
typedef unsigned short u16;

#if __has_builtin(__builtin_amdgcn_exp2f)
#define EXP2(x) __builtin_amdgcn_exp2f(x)
#else
#define EXP2(x) __expf((x) * 0.6931471805599453f)
#endif

#define BAR() asm volatile("s_barrier" ::: "memory")
#define WAITV0() asm volatile("s_waitcnt vmcnt(0)" ::: "memory")
#define QSCALE 0.1803368801111137f   /* (1/8) * log2(e) */

__device__ inline u16 f2bf(float f) {
  union { float f; unsigned u; } v; v.f = f;
  unsigned r = v.u + 0x7fff + ((v.u >> 16) & 1);   // RNE
  return (u16)(r >> 16);
}

__device__ inline unsigned cvtpk(float lo, float hi_) {
  unsigned d;
  asm("v_cvt_pk_bf16_f32 %0, %1, %2" : "=v"(d) : "v"(lo), "v"(hi_));
  return d;
}

__device__ inline void perm32swap(unsigned& a, unsigned& b) {
  asm volatile("v_permlane32_swap_b32 %0, %1" : "+v"(a), "+v"(b));
}

__device__ inline void gload_lds16(const void* g, void* l) {
  __builtin_amdgcn_global_load_lds(
      (const __attribute__((address_space(1))) void*)g,
      (__attribute__((address_space(3))) void*)l, 16, 0, 0);
}

// ---------------- fused prep: X fp32->bf16 + 4 weight transposes ----------------
__global__ __launch_bounds__(256) void prep_kernel(
    const float* __restrict__ x, u16* __restrict__ xb,
    const float* __restrict__ wq, const float* __restrict__ wk,
    const float* __restrict__ wv, const float* __restrict__ wo,
    u16* __restrict__ wqkvT, u16* __restrict__ woT) {
  __shared__ float t[32][33];
  const int bid = blockIdx.x, tid = threadIdx.x;
  if (bid < 8192) {
    int i = bid * 256 + tid;
    float4 v = reinterpret_cast<const float4*>(x)[i];
    ushort4 o;
    o.x = f2bf(v.x); o.y = f2bf(v.y); o.z = f2bf(v.z); o.w = f2bf(v.w);
    reinterpret_cast<ushort4*>(xb)[i] = o;
    return;
  }
  const int wb = bid - 8192;
  const int z = wb >> 10;
  const int rem = wb & 1023;
  const int bx = rem & 31, by = rem >> 5;
  const float* w = (z == 0) ? wq : (z == 1) ? wk : (z == 2) ? wv : wo;
  u16* wt = (z < 3) ? (wqkvT + (size_t)z * 1024 * 1024) : woT;
  const float sc = (z == 0) ? QSCALE : 1.0f;
  const int tx = tid & 31, ty = tid >> 5;
  const int n0 = bx * 32, k0 = by * 32;
#pragma unroll
  for (int j = 0; j < 32; j += 8)
    t[ty + j][tx] = w[(size_t)(k0 + ty + j) * D_DIM + n0 + tx];
  __syncthreads();
#pragma unroll
  for (int j = 0; j < 32; j += 8)
    wt[(size_t)(n0 + ty + j) * D_DIM + k0 + tx] = f2bf(t[tx][ty + j] * sc);
}

// ============ QKV GEMM: 128x128, BK=64 single-buffer 2-sync, T2-swizzled LDS ============
// Half the barrier/drain envelopes of BK=32 (16 K-steps x 32 MFMA). LDS 32KB.
// Swizzle (both-sides, R5-proven): source chunk (tid&7)^((tid>>3)&7); read byte ^ (fr&7)<<4.
__global__ __launch_bounds__(256) void gemm_qkv_kernel(
    const u16* __restrict__ A, const u16* __restrict__ Bt,
    u16* __restrict__ Qb, u16* __restrict__ KP, u16* __restrict__ VP) {
  __shared__ u16 lA[128 * 64];
  __shared__ u16 lB[128 * 64];
  const int tid = threadIdx.x, wid = tid >> 6, lane = tid & 63;
  const int wg = blockIdx.x;                       // [0,1536)
  const int swz = (wg & 7) * 192 + (wg >> 3);      // XCD-chunk (1536 % 8 == 0)
  const int bm = swz / 24, bn = swz % 24;
  const int fr = lane & 15, fq = lane >> 4;
  const int rx = (fr & 7) << 4;                    // read-side byte XOR

  // staging geometry: pass p covers rows p*32..p*32+31; thread row tid>>3, swizzled chunk
  const int srow = tid >> 3;                       // 0..31
  const int schunk = (tid & 7) ^ ((tid >> 3) & 7); // row&7 == (tid>>3)&7 for every pass
  const u16* gA = A + (size_t)(bm * 128 + srow) * 1024 + schunk * 8;
  const u16* gB = Bt + (size_t)(bn * 128 + srow) * 1024 + schunk * 8;
  u16* dA = &lA[wid * 8 * 64];                     // wave-uniform dest base (8 rows/wave/pass)
  u16* dB = &lB[wid * 8 * 64];

  f32x4 acc[4][4] = {};
  const int wm = (wid >> 1) * 64, wn = (wid & 1) * 64;

  for (int k0 = 0; k0 < 1024; k0 += 64) {
#pragma unroll
    for (int p = 0; p < 4; p++) {
      gload_lds16(gA + k0 + (size_t)p * 32 * 1024, dA + p * 32 * 64);
      gload_lds16(gB + k0 + (size_t)p * 32 * 1024, dB + p * 32 * 64);
    }
    __syncthreads();
    // K-half 0
    {
      bf16x8 fa[4], fb[4];
#pragma unroll
      for (int i = 0; i < 4; i++) {
        fa[i] = *(const bf16x8*)((const char*)lA + (wm + i * 16 + fr) * 128 + ((fq << 4) ^ rx));
        fb[i] = *(const bf16x8*)((const char*)lB + (wn + i * 16 + fr) * 128 + ((fq << 4) ^ rx));
      }
#pragma unroll
      for (int i = 0; i < 4; i++)
#pragma unroll
        for (int j = 0; j < 4; j++)
          acc[i][j] = __builtin_amdgcn_mfma_f32_16x16x32_bf16(fa[i], fb[j], acc[i][j], 0, 0, 0);
    }
    // K-half 1
    {
      bf16x8 fa[4], fb[4];
#pragma unroll
      for (int i = 0; i < 4; i++) {
        fa[i] = *(const bf16x8*)((const char*)lA + (wm + i * 16 + fr) * 128 + (((4 + fq) << 4) ^ rx));
        fb[i] = *(const bf16x8*)((const char*)lB + (wn + i * 16 + fr) * 128 + (((4 + fq) << 4) ^ rx));
      }
#pragma unroll
      for (int i = 0; i < 4; i++)
#pragma unroll
        for (int j = 0; j < 4; j++)
          acc[i][j] = __builtin_amdgcn_mfma_f32_16x16x32_bf16(fa[i], fb[j], acc[i][j], 0, 0, 0);
    }
    __syncthreads();
  }

  const int col0 = bn * 128;   // wave-uniform region select
  if (col0 < 1024) {
#pragma unroll
    for (int i = 0; i < 4; i++)
#pragma unroll
      for (int j = 0; j < 4; j++)
#pragma unroll
        for (int r = 0; r < 4; r++) {
          int row = bm * 128 + wm + i * 16 + fq * 4 + r;
          int col = col0 + wn + j * 16 + fr;
          Qb[(size_t)row * 1024 + col] = f2bf(acc[i][j][r]);
        }
  } else if (col0 < 2048) {
#pragma unroll
    for (int i = 0; i < 4; i++)
#pragma unroll
      for (int j = 0; j < 4; j++) {
        int col = col0 + wn + j * 16 + fr;
        int ck = col - 1024;
        int h = ck >> 6, d = ck & 63;
        int sfr = d >> 4, e = d & 7, hb = (d >> 3) & 1;
#pragma unroll
        for (int r = 0; r < 4; r++) {
          int row = bm * 128 + wm + i * 16 + fq * 4 + r;
          int b = row >> 11, sp = row & 2047;
          int bh = b * 16 + h, jt = sp >> 5;
          int lanep = (sp & 31) + 32 * hb;
          KP[((size_t)(bh * 64 + jt) * 4 + sfr) * 512 + lanep * 8 + e] = f2bf(acc[i][j][r]);
        }
      }
  } else {
#pragma unroll
    for (int i = 0; i < 4; i++)
#pragma unroll
      for (int j = 0; j < 4; j++) {
        int col = col0 + wn + j * 16 + fr;
        int cv = col - 2048;
        int h = cv >> 6, d = cv & 63;
        int R0 = bm * 128 + wm + i * 16 + fq * 4;
        int b = R0 >> 11, sp0 = R0 & 2047;
        int bh = b * 16 + h, jt = sp0 >> 5;
        int c = (d >> 5) * 2 + ((sp0 >> 4) & 1);
        int lanep = (d & 31) + 32 * ((sp0 >> 3) & 1);
        int e0 = sp0 & 7;
        ushort4 ov;
        ov.x = f2bf(acc[i][j][0]); ov.y = f2bf(acc[i][j][1]);
        ov.z = f2bf(acc[i][j][2]); ov.w = f2bf(acc[i][j][3]);
        *(ushort4*)(VP + ((size_t)(bh * 64 + jt) * 4 + c) * 512 + lanep * 8 + e0) = ov;
      }
  }
}

// ============ out-proj GEMM: 128x128, dbuf one-barrier (R7-measured) ============
__global__ __launch_bounds__(256) void gemm_out_kernel(
    const u16* __restrict__ A, const u16* __restrict__ Bt,
    float* __restrict__ C, const float* __restrict__ bias) {
  __shared__ u16 lA[2][128 * 32];
  __shared__ u16 lB[2][128 * 32];
  const int tid = threadIdx.x, wid = tid >> 6, lane = tid & 63;
  const int bm = blockIdx.y, bn = blockIdx.x;
  const int fr = lane & 15, fq = lane >> 4;
  const int r0 = wid * 32;
  const int srow = lane >> 2, scol = (lane & 3) * 8;
  const u16* gA = A + (size_t)(bm * 128 + r0 + srow) * 1024 + scol;
  const u16* gB = Bt + (size_t)(bn * 128 + r0 + srow) * 1024 + scol;

  f32x4 acc[4][4] = {};
  const int wm = (wid >> 1) * 64, wn = (wid & 1) * 64;

  gload_lds16(gA,             &lA[0][r0 * 32]);
  gload_lds16(gA + 16 * 1024, &lA[0][r0 * 32 + 16 * 32]);
  gload_lds16(gB,             &lB[0][r0 * 32]);
  gload_lds16(gB + 16 * 1024, &lB[0][r0 * 32 + 16 * 32]);
  WAITV0();
  BAR();

#pragma unroll
  for (int k0 = 0; k0 < 1024; k0 += 32) {
    const int cur = (k0 >> 5) & 1, nxt = cur ^ 1;
    if (k0 + 32 < 1024) {
      gload_lds16(gA + k0 + 32,             &lA[nxt][r0 * 32]);
      gload_lds16(gA + k0 + 32 + 16 * 1024, &lA[nxt][r0 * 32 + 16 * 32]);
      gload_lds16(gB + k0 + 32,             &lB[nxt][r0 * 32]);
      gload_lds16(gB + k0 + 32 + 16 * 1024, &lB[nxt][r0 * 32 + 16 * 32]);
    }
    bf16x8 fa[4], fb[4];
#pragma unroll
    for (int i = 0; i < 4; i++) {
      fa[i] = *(const bf16x8*)&lA[cur][(wm + i * 16 + fr) * 32 + fq * 8];
      fb[i] = *(const bf16x8*)&lB[cur][(wn + i * 16 + fr) * 32 + fq * 8];
    }
#pragma unroll
    for (int i = 0; i < 4; i++)
#pragma unroll
      for (int j = 0; j < 4; j++)
        acc[i][j] = __builtin_amdgcn_mfma_f32_16x16x32_bf16(fa[i], fb[j], acc[i][j], 0, 0, 0);
    WAITV0();
    BAR();
  }

#pragma unroll
  for (int i = 0; i < 4; i++)
#pragma unroll
    for (int j = 0; j < 4; j++)
#pragma unroll
      for (int r = 0; r < 4; r++) {
        int row = bm * 128 + wm + i * 16 + fq * 4 + r;
        int col = bn * 128 + wn + j * 16 + fr;
        C[(size_t)row * 1024 + col] = acc[i][j][r] + bias[col];
      }
}

// ---------------- flash attention (causal), swapped-operand 32x32 MFMA (R10) ----------------
__global__ __launch_bounds__(256) void attn_kernel(
    const u16* __restrict__ Q, const u16* __restrict__ KP,
    const u16* __restrict__ VP, u16* __restrict__ O) {
  const int tid = threadIdx.x, wid = tid >> 6, lane = tid & 63;
  const int lq = lane & 31, hi = lane >> 5;
  int f = blockIdx.x;
  int xcd = f & 7, kk = f >> 3;
  int bh = xcd * 8 + (kk & 7);
  int qblk = 15 - (kk >> 3);
  int b = bh >> 4, h = bh & 15;
  int q0 = qblk * 128 + wid * 32;
  int q = q0 + lq;

  const u16* Qrow = Q + (size_t)(b * S_LEN + q) * D_DIM + h * HDIM;
  bf16x8 qf[4];
#pragma unroll
  for (int s = 0; s < 4; s++)
    qf[s] = *(const bf16x8*)(Qrow + s * 16 + hi * 8);

  const bf16x8* KPt = (const bf16x8*)KP + (size_t)bh * 64 * 4 * 64;
  const bf16x8* VPt = (const bf16x8*)VP + (size_t)bh * 64 * 4 * 64;

  f32x16 acc0 = {}, acc1 = {};
  float m = -3.0e38f, l = 0.f;
  const int nt = qblk * 4 + wid + 1;

  for (int t = 0; t < nt; ++t) {
    const int j0 = t * 32;
    const size_t fb = (size_t)t * 4 * 64 + lane;
    bf16x8 kf0 = KPt[fb], kf1 = KPt[fb + 64], kf2 = KPt[fb + 128], kf3 = KPt[fb + 192];
    bf16x8 vf00 = VPt[fb], vf01 = VPt[fb + 64], vf10 = VPt[fb + 128], vf11 = VPt[fb + 192];

    f32x16 sa = {};
    __builtin_amdgcn_s_setprio(1);
    sa = __builtin_amdgcn_mfma_f32_32x32x16_bf16(kf0, qf[0], sa, 0, 0, 0);
    sa = __builtin_amdgcn_mfma_f32_32x32x16_bf16(kf1, qf[1], sa, 0, 0, 0);
    sa = __builtin_amdgcn_mfma_f32_32x32x16_bf16(kf2, qf[2], sa, 0, 0, 0);
    sa = __builtin_amdgcn_mfma_f32_32x32x16_bf16(kf3, qf[3], sa, 0, 0, 0);
    __builtin_amdgcn_s_setprio(0);

    float p[16];
#pragma unroll
    for (int r = 0; r < 16; ++r) p[r] = sa[r];

    if (t == nt - 1) {
#pragma unroll
      for (int r = 0; r < 16; ++r) {
        int kidx = j0 + (r & 3) + 8 * (r >> 2) + 4 * hi;
        if (kidx > q) p[r] = -3.0e38f;
      }
    }

    float x8[8], x4[4], x2[2];
#pragma unroll
    for (int i = 0; i < 8; ++i) x8[i] = fmaxf(p[2 * i], p[2 * i + 1]);
#pragma unroll
    for (int i = 0; i < 4; ++i) x4[i] = fmaxf(x8[2 * i], x8[2 * i + 1]);
    x2[0] = fmaxf(x4[0], x4[1]); x2[1] = fmaxf(x4[2], x4[3]);
    float pm = fmaxf(x2[0], x2[1]);
    pm = fmaxf(pm, __shfl_xor(pm, 32));

    if (__any(pm > m + 11.5f)) {
      float mn = fmaxf(m, pm);
      float sc = EXP2(m - mn);
      l *= sc;
#pragma unroll
      for (int r = 0; r < 16; ++r) { acc0[r] *= sc; acc1[r] *= sc; }
      m = mn;
    }

    float rs = 0.f;
#pragma unroll
    for (int r = 0; r < 16; ++r) { p[r] = EXP2(p[r] - m); rs += p[r]; }
    rs += __shfl_xor(rs, 32);
    l += rs;

    unsigned c0 = cvtpk(p[0],  p[1]),  c1 = cvtpk(p[2],  p[3]);
    unsigned c2 = cvtpk(p[4],  p[5]),  c3 = cvtpk(p[6],  p[7]);
    unsigned c4 = cvtpk(p[8],  p[9]),  c5 = cvtpk(p[10], p[11]);
    unsigned c6 = cvtpk(p[12], p[13]), c7 = cvtpk(p[14], p[15]);
    perm32swap(c0, c2); perm32swap(c1, c3);
    perm32swap(c4, c6); perm32swap(c5, c7);
    union U4 { unsigned u[4]; bf16x8 v; } F0, F1;
    F0.u[0] = c0; F0.u[1] = c1; F0.u[2] = c2; F0.u[3] = c3;
    F1.u[0] = c4; F1.u[1] = c5; F1.u[2] = c6; F1.u[3] = c7;

    __builtin_amdgcn_s_setprio(1);
    acc0 = __builtin_amdgcn_mfma_f32_32x32x16_bf16(vf00, F0.v, acc0, 0, 0, 0);
    acc0 = __builtin_amdgcn_mfma_f32_32x32x16_bf16(vf01, F1.v, acc0, 0, 0, 0);
    acc1 = __builtin_amdgcn_mfma_f32_32x32x16_bf16(vf10, F0.v, acc1, 0, 0, 0);
    acc1 = __builtin_amdgcn_mfma_f32_32x32x16_bf16(vf11, F1.v, acc1, 0, 0, 0);
    __builtin_amdgcn_s_setprio(0);
  }

  float inv = 1.f / l;
  u16* Orow = O + (size_t)(b * S_LEN + q) * D_DIM + h * HDIM;
#pragma unroll
  for (int g = 0; g < 4; ++g) {
    ushort4 o4;
    o4.x = f2bf(acc0[g * 4 + 0] * inv);
    o4.y = f2bf(acc0[g * 4 + 1] * inv);
    o4.z = f2bf(acc0[g * 4 + 2] * inv);
    o4.w = f2bf(acc0[g * 4 + 3] * inv);
    *(ushort4*)(Orow + 8 * g + 4 * hi) = o4;
  }
#pragma unroll
  for (int g = 0; g < 4; ++g) {
    ushort4 o4;
    o4.x = f2bf(acc1[g * 4 + 0] * inv);
    o4.y = f2bf(acc1[g * 4 + 1] * inv);
    o4.z = f2bf(acc1[g * 4 + 2] * inv);
    o4.w = f2bf(acc1[g * 4 + 3] * inv);
    *(ushort4*)(Orow + 32 + 8 * g + 4 * hi) = o4;
  }
}

// ---------------- launcher ----------------
extern "C" void kernel_launch(void* const* d_in, const int* in_sizes, int n_in,
                              void* d_out, int out_size, void* d_ws, size_t ws_size,
                              hipStream_t stream) {
  const float* x  = (const float*)d_in[0];
  const float* wq = (const float*)d_in[1];
  const float* wk = (const float*)d_in[2];
  const float* wv = (const float*)d_in[3];
  const float* wo = (const float*)d_in[4];
  const float* ob = (const float*)d_in[5];
  float* out = (float*)d_out;

  char* ws = (char*)d_ws;
  u16* Xb    = (u16*)(ws);                              // slot A: Xb then Ab
  u16* Ab    = (u16*)(ws);
  u16* Qb    = (u16*)(ws + (size_t)16 * 1024 * 1024);   // 16 MB
  u16* KPb   = (u16*)(ws + (size_t)32 * 1024 * 1024);   // 16 MB
  u16* VPb   = (u16*)(ws + (size_t)48 * 1024 * 1024);   // 16 MB
  u16* WqkvT = (u16*)(ws + (size_t)64 * 1024 * 1024);   // 6 MB
  u16* WoT   = (u16*)(ws + (size_t)70 * 1024 * 1024);   // 2 MB

  // fused prep: X convert (8192 blocks) + 4 weight transposes (4096 blocks)
  prep_kernel<<<dim3(12288), 256, 0, stream>>>(x, Xb, wq, wk, wv, wo, WqkvT, WoT);

  // fused QKV projection [8192,1024]x[1024,3072] with fused Q/K/V pack epilogue
  gemm_qkv_kernel<<<dim3(1536), 256, 0, stream>>>(Xb, WqkvT, Qb, KPb, VPb);

  attn_kernel<<<dim3(1024), 256, 0, stream>>>(Qb, KPb, VPb, Ab);

  // out projection [8192,1024]x[1024,1024] + bias, fp32 out
  gemm_out_kernel<<<dim3(8, 64), 256, 0, stream>>>(Ab, WoT, out, ob);
}

// Round 15
// 164.899 us; speedup vs baseline: 1.2304x; 1.0200x over previous
//
#include <hip/hip_runtime.h>
#include <hip/hip_bf16.h>

#define S_LEN 2048
#define D_DIM 1024
#define NHEAD 16
#define HDIM  64
#define BATCH 4
#define MROWS (BATCH*S_LEN)   /* 8192 */

typedef short bf16x8 __attribute__((ext_vector_type(8)));
typedef float f32x4  __attribute__((ext_vector_type(4)));
typedef float f32x16 __attribute__((ext_vector_type(16)));
typedef unsigned short u16;

#if __has_builtin(__builtin_amdgcn_exp2f)
#define EXP2(x) __builtin_amdgcn_exp2f(x)
#else
#define EXP2(x) __expf((x) * 0.6931471805599453f)
#endif

#define QSCALE 0.1803368801111137f   /* (1/8) * log2(e) */

__device__ inline u16 f2bf(float f) {
  union { float f; unsigned u; } v; v.f = f;
  unsigned r = v.u + 0x7fff + ((v.u >> 16) & 1);   // RNE
  return (u16)(r >> 16);
}

__device__ inline unsigned cvtpk(float lo, float hi_) {
  unsigned d;
  asm("v_cvt_pk_bf16_f32 %0, %1, %2" : "=v"(d) : "v"(lo), "v"(hi_));
  return d;
}

__device__ inline void perm32swap(unsigned& a, unsigned& b) {
  asm volatile("v_permlane32_swap_b32 %0, %1" : "+v"(a), "+v"(b));
}

__device__ inline void gload_lds16(const void* g, void* l) {
  __builtin_amdgcn_global_load_lds(
      (const __attribute__((address_space(1))) void*)g,
      (__attribute__((address_space(3))) void*)l, 16, 0, 0);
}

// ---------------- fused prep: X fp32->bf16 + 4 weight transposes ----------------
__global__ __launch_bounds__(256) void prep_kernel(
    const float* __restrict__ x, u16* __restrict__ xb,
    const float* __restrict__ wq, const float* __restrict__ wk,
    const float* __restrict__ wv, const float* __restrict__ wo,
    u16* __restrict__ wqkvT, u16* __restrict__ woT) {
  __shared__ float t[32][33];
  const int bid = blockIdx.x, tid = threadIdx.x;
  if (bid < 8192) {
    int i = bid * 256 + tid;
    float4 v = reinterpret_cast<const float4*>(x)[i];
    ushort4 o;
    o.x = f2bf(v.x); o.y = f2bf(v.y); o.z = f2bf(v.z); o.w = f2bf(v.w);
    reinterpret_cast<ushort4*>(xb)[i] = o;
    return;
  }
  const int wb = bid - 8192;
  const int z = wb >> 10;
  const int rem = wb & 1023;
  const int bx = rem & 31, by = rem >> 5;
  const float* w = (z == 0) ? wq : (z == 1) ? wk : (z == 2) ? wv : wo;
  u16* wt = (z < 3) ? (wqkvT + (size_t)z * 1024 * 1024) : woT;
  const float sc = (z == 0) ? QSCALE : 1.0f;
  const int tx = tid & 31, ty = tid >> 5;
  const int n0 = bx * 32, k0 = by * 32;
#pragma unroll
  for (int j = 0; j < 32; j += 8)
    t[ty + j][tx] = w[(size_t)(k0 + ty + j) * D_DIM + n0 + tx];
  __syncthreads();
#pragma unroll
  for (int j = 0; j < 32; j += 8)
    wt[(size_t)(n0 + ty + j) * D_DIM + k0 + tx] = f2bf(t[tx][ty + j] * sc);
}

// ============ QKV GEMM: 128x128, BK=64 single-buffer 2-sync, T2-swizzled LDS ============
__global__ __launch_bounds__(256) void gemm_qkv_kernel(
    const u16* __restrict__ A, const u16* __restrict__ Bt,
    u16* __restrict__ Qb, u16* __restrict__ KP, u16* __restrict__ VP) {
  __shared__ u16 lA[128 * 64];
  __shared__ u16 lB[128 * 64];
  const int tid = threadIdx.x, wid = tid >> 6, lane = tid & 63;
  const int wg = blockIdx.x;                       // [0,1536)
  const int swz = (wg & 7) * 192 + (wg >> 3);      // XCD-chunk (1536 % 8 == 0)
  const int bm = swz / 24, bn = swz % 24;
  const int fr = lane & 15, fq = lane >> 4;
  const int rx = (fr & 7) << 4;                    // read-side byte XOR

  const int srow = tid >> 3;                       // 0..31
  const int schunk = (tid & 7) ^ ((tid >> 3) & 7);
  const u16* gA = A + (size_t)(bm * 128 + srow) * 1024 + schunk * 8;
  const u16* gB = Bt + (size_t)(bn * 128 + srow) * 1024 + schunk * 8;
  u16* dA = &lA[wid * 8 * 64];
  u16* dB = &lB[wid * 8 * 64];

  f32x4 acc[4][4] = {};
  const int wm = (wid >> 1) * 64, wn = (wid & 1) * 64;

  for (int k0 = 0; k0 < 1024; k0 += 64) {
#pragma unroll
    for (int p = 0; p < 4; p++) {
      gload_lds16(gA + k0 + (size_t)p * 32 * 1024, dA + p * 32 * 64);
      gload_lds16(gB + k0 + (size_t)p * 32 * 1024, dB + p * 32 * 64);
    }
    __syncthreads();
    {
      bf16x8 fa[4], fb[4];
#pragma unroll
      for (int i = 0; i < 4; i++) {
        fa[i] = *(const bf16x8*)((const char*)lA + (wm + i * 16 + fr) * 128 + ((fq << 4) ^ rx));
        fb[i] = *(const bf16x8*)((const char*)lB + (wn + i * 16 + fr) * 128 + ((fq << 4) ^ rx));
      }
#pragma unroll
      for (int i = 0; i < 4; i++)
#pragma unroll
        for (int j = 0; j < 4; j++)
          acc[i][j] = __builtin_amdgcn_mfma_f32_16x16x32_bf16(fa[i], fb[j], acc[i][j], 0, 0, 0);
    }
    {
      bf16x8 fa[4], fb[4];
#pragma unroll
      for (int i = 0; i < 4; i++) {
        fa[i] = *(const bf16x8*)((const char*)lA + (wm + i * 16 + fr) * 128 + (((4 + fq) << 4) ^ rx));
        fb[i] = *(const bf16x8*)((const char*)lB + (wn + i * 16 + fr) * 128 + (((4 + fq) << 4) ^ rx));
      }
#pragma unroll
      for (int i = 0; i < 4; i++)
#pragma unroll
        for (int j = 0; j < 4; j++)
          acc[i][j] = __builtin_amdgcn_mfma_f32_16x16x32_bf16(fa[i], fb[j], acc[i][j], 0, 0, 0);
    }
    __syncthreads();
  }

  const int col0 = bn * 128;   // wave-uniform region select
  if (col0 < 1024) {
#pragma unroll
    for (int i = 0; i < 4; i++)
#pragma unroll
      for (int j = 0; j < 4; j++)
#pragma unroll
        for (int r = 0; r < 4; r++) {
          int row = bm * 128 + wm + i * 16 + fq * 4 + r;
          int col = col0 + wn + j * 16 + fr;
          Qb[(size_t)row * 1024 + col] = f2bf(acc[i][j][r]);
        }
  } else if (col0 < 2048) {
#pragma unroll
    for (int i = 0; i < 4; i++)
#pragma unroll
      for (int j = 0; j < 4; j++) {
        int col = col0 + wn + j * 16 + fr;
        int ck = col - 1024;
        int h = ck >> 6, d = ck & 63;
        int sfr = d >> 4, e = d & 7, hb = (d >> 3) & 1;
#pragma unroll
        for (int r = 0; r < 4; r++) {
          int row = bm * 128 + wm + i * 16 + fq * 4 + r;
          int b = row >> 11, sp = row & 2047;
          int bh = b * 16 + h, jt = sp >> 5;
          int lanep = (sp & 31) + 32 * hb;
          KP[((size_t)(bh * 64 + jt) * 4 + sfr) * 512 + lanep * 8 + e] = f2bf(acc[i][j][r]);
        }
      }
  } else {
#pragma unroll
    for (int i = 0; i < 4; i++)
#pragma unroll
      for (int j = 0; j < 4; j++) {
        int col = col0 + wn + j * 16 + fr;
        int cv = col - 2048;
        int h = cv >> 6, d = cv & 63;
        int R0 = bm * 128 + wm + i * 16 + fq * 4;
        int b = R0 >> 11, sp0 = R0 & 2047;
        int bh = b * 16 + h, jt = sp0 >> 5;
        int c = (d >> 5) * 2 + ((sp0 >> 4) & 1);
        int lanep = (d & 31) + 32 * ((sp0 >> 3) & 1);
        int e0 = sp0 & 7;
        ushort4 ov;
        ov.x = f2bf(acc[i][j][0]); ov.y = f2bf(acc[i][j][1]);
        ov.z = f2bf(acc[i][j][2]); ov.w = f2bf(acc[i][j][3]);
        *(ushort4*)(VP + ((size_t)(bh * 64 + jt) * 4 + c) * 512 + lanep * 8 + e0) = ov;
      }
  }
}

// ============ out-proj GEMM: 128x128, BK=64 single-buffer 2-sync, T2-swizzled ============
// Same K-loop body as gemm_qkv (R14-proven); fp32 C + bias epilogue. Grid 512 1D, XCD swizzle.
__global__ __launch_bounds__(256) void gemm_out_kernel(
    const u16* __restrict__ A, const u16* __restrict__ Bt,
    float* __restrict__ C, const float* __restrict__ bias) {
  __shared__ u16 lA[128 * 64];
  __shared__ u16 lB[128 * 64];
  const int tid = threadIdx.x, wid = tid >> 6, lane = tid & 63;
  const int wg = blockIdx.x;                       // [0,512)
  const int swz = (wg & 7) * 64 + (wg >> 3);       // XCD-chunk (512 % 8 == 0)
  const int bm = swz >> 3, bn = swz & 7;
  const int fr = lane & 15, fq = lane >> 4;
  const int rx = (fr & 7) << 4;

  const int srow = tid >> 3;
  const int schunk = (tid & 7) ^ ((tid >> 3) & 7);
  const u16* gA = A + (size_t)(bm * 128 + srow) * 1024 + schunk * 8;
  const u16* gB = Bt + (size_t)(bn * 128 + srow) * 1024 + schunk * 8;
  u16* dA = &lA[wid * 8 * 64];
  u16* dB = &lB[wid * 8 * 64];

  f32x4 acc[4][4] = {};
  const int wm = (wid >> 1) * 64, wn = (wid & 1) * 64;

  for (int k0 = 0; k0 < 1024; k0 += 64) {
#pragma unroll
    for (int p = 0; p < 4; p++) {
      gload_lds16(gA + k0 + (size_t)p * 32 * 1024, dA + p * 32 * 64);
      gload_lds16(gB + k0 + (size_t)p * 32 * 1024, dB + p * 32 * 64);
    }
    __syncthreads();
    {
      bf16x8 fa[4], fb[4];
#pragma unroll
      for (int i = 0; i < 4; i++) {
        fa[i] = *(const bf16x8*)((const char*)lA + (wm + i * 16 + fr) * 128 + ((fq << 4) ^ rx));
        fb[i] = *(const bf16x8*)((const char*)lB + (wn + i * 16 + fr) * 128 + ((fq << 4) ^ rx));
      }
#pragma unroll
      for (int i = 0; i < 4; i++)
#pragma unroll
        for (int j = 0; j < 4; j++)
          acc[i][j] = __builtin_amdgcn_mfma_f32_16x16x32_bf16(fa[i], fb[j], acc[i][j], 0, 0, 0);
    }
    {
      bf16x8 fa[4], fb[4];
#pragma unroll
      for (int i = 0; i < 4; i++) {
        fa[i] = *(const bf16x8*)((const char*)lA + (wm + i * 16 + fr) * 128 + (((4 + fq) << 4) ^ rx));
        fb[i] = *(const bf16x8*)((const char*)lB + (wn + i * 16 + fr) * 128 + (((4 + fq) << 4) ^ rx));
      }
#pragma unroll
      for (int i = 0; i < 4; i++)
#pragma unroll
        for (int j = 0; j < 4; j++)
          acc[i][j] = __builtin_amdgcn_mfma_f32_16x16x32_bf16(fa[i], fb[j], acc[i][j], 0, 0, 0);
    }
    __syncthreads();
  }

#pragma unroll
  for (int i = 0; i < 4; i++)
#pragma unroll
    for (int j = 0; j < 4; j++)
#pragma unroll
      for (int r = 0; r < 4; r++) {
        int row = bm * 128 + wm + i * 16 + fq * 4 + r;
        int col = bn * 128 + wn + j * 16 + fr;
        C[(size_t)row * 1024 + col] = acc[i][j][r] + bias[col];
      }
}

// ---------------- flash attention (causal), swapped-operand 32x32 MFMA (R10) ----------------
__global__ __launch_bounds__(256) void attn_kernel(
    const u16* __restrict__ Q, const u16* __restrict__ KP,
    const u16* __restrict__ VP, u16* __restrict__ O) {
  const int tid = threadIdx.x, wid = tid >> 6, lane = tid & 63;
  const int lq = lane & 31, hi = lane >> 5;
  int f = blockIdx.x;
  int xcd = f & 7, kk = f >> 3;
  int bh = xcd * 8 + (kk & 7);
  int qblk = 15 - (kk >> 3);
  int b = bh >> 4, h = bh & 15;
  int q0 = qblk * 128 + wid * 32;
  int q = q0 + lq;

  const u16* Qrow = Q + (size_t)(b * S_LEN + q) * D_DIM + h * HDIM;
  bf16x8 qf[4];
#pragma unroll
  for (int s = 0; s < 4; s++)
    qf[s] = *(const bf16x8*)(Qrow + s * 16 + hi * 8);

  const bf16x8* KPt = (const bf16x8*)KP + (size_t)bh * 64 * 4 * 64;
  const bf16x8* VPt = (const bf16x8*)VP + (size_t)bh * 64 * 4 * 64;

  f32x16 acc0 = {}, acc1 = {};
  float m = -3.0e38f, l = 0.f;
  const int nt = qblk * 4 + wid + 1;

  for (int t = 0; t < nt; ++t) {
    const int j0 = t * 32;
    const size_t fb = (size_t)t * 4 * 64 + lane;
    bf16x8 kf0 = KPt[fb], kf1 = KPt[fb + 64], kf2 = KPt[fb + 128], kf3 = KPt[fb + 192];
    bf16x8 vf00 = VPt[fb], vf01 = VPt[fb + 64], vf10 = VPt[fb + 128], vf11 = VPt[fb + 192];

    f32x16 sa = {};
    __builtin_amdgcn_s_setprio(1);
    sa = __builtin_amdgcn_mfma_f32_32x32x16_bf16(kf0, qf[0], sa, 0, 0, 0);
    sa = __builtin_amdgcn_mfma_f32_32x32x16_bf16(kf1, qf[1], sa, 0, 0, 0);
    sa = __builtin_amdgcn_mfma_f32_32x32x16_bf16(kf2, qf[2], sa, 0, 0, 0);
    sa = __builtin_amdgcn_mfma_f32_32x32x16_bf16(kf3, qf[3], sa, 0, 0, 0);
    __builtin_amdgcn_s_setprio(0);

    float p[16];
#pragma unroll
    for (int r = 0; r < 16; ++r) p[r] = sa[r];

    if (t == nt - 1) {
#pragma unroll
      for (int r = 0; r < 16; ++r) {
        int kidx = j0 + (r & 3) + 8 * (r >> 2) + 4 * hi;
        if (kidx > q) p[r] = -3.0e38f;
      }
    }

    float x8[8], x4[4], x2[2];
#pragma unroll
    for (int i = 0; i < 8; ++i) x8[i] = fmaxf(p[2 * i], p[2 * i + 1]);
#pragma unroll
    for (int i = 0; i < 4; ++i) x4[i] = fmaxf(x8[2 * i], x8[2 * i + 1]);
    x2[0] = fmaxf(x4[0], x4[1]); x2[1] = fmaxf(x4[2], x4[3]);
    float pm = fmaxf(x2[0], x2[1]);
    pm = fmaxf(pm, __shfl_xor(pm, 32));

    if (__any(pm > m + 11.5f)) {
      float mn = fmaxf(m, pm);
      float sc = EXP2(m - mn);
      l *= sc;
#pragma unroll
      for (int r = 0; r < 16; ++r) { acc0[r] *= sc; acc1[r] *= sc; }
      m = mn;
    }

    float rs = 0.f;
#pragma unroll
    for (int r = 0; r < 16; ++r) { p[r] = EXP2(p[r] - m); rs += p[r]; }
    rs += __shfl_xor(rs, 32);
    l += rs;

    unsigned c0 = cvtpk(p[0],  p[1]),  c1 = cvtpk(p[2],  p[3]);
    unsigned c2 = cvtpk(p[4],  p[5]),  c3 = cvtpk(p[6],  p[7]);
    unsigned c4 = cvtpk(p[8],  p[9]),  c5 = cvtpk(p[10], p[11]);
    unsigned c6 = cvtpk(p[12], p[13]), c7 = cvtpk(p[14], p[15]);
    perm32swap(c0, c2); perm32swap(c1, c3);
    perm32swap(c4, c6); perm32swap(c5, c7);
    union U4 { unsigned u[4]; bf16x8 v; } F0, F1;
    F0.u[0] = c0; F0.u[1] = c1; F0.u[2] = c2; F0.u[3] = c3;
    F1.u[0] = c4; F1.u[1] = c5; F1.u[2] = c6; F1.u[3] = c7;

    __builtin_amdgcn_s_setprio(1);
    acc0 = __builtin_amdgcn_mfma_f32_32x32x16_bf16(vf00, F0.v, acc0, 0, 0, 0);
    acc0 = __builtin_amdgcn_mfma_f32_32x32x16_bf16(vf01, F1.v, acc0, 0, 0, 0);
    acc1 = __builtin_amdgcn_mfma_f32_32x32x16_bf16(vf10, F0.v, acc1, 0, 0, 0);
    acc1 = __builtin_amdgcn_mfma_f32_32x32x16_bf16(vf11, F1.v, acc1, 0, 0, 0);
    __builtin_amdgcn_s_setprio(0);
  }

  float inv = 1.f / l;
  u16* Orow = O + (size_t)(b * S_LEN + q) * D_DIM + h * HDIM;
#pragma unroll
  for (int g = 0; g < 4; ++g) {
    ushort4 o4;
    o4.x = f2bf(acc0[g * 4 + 0] * inv);
    o4.y = f2bf(acc0[g * 4 + 1] * inv);
    o4.z = f2bf(acc0[g * 4 + 2] * inv);
    o4.w = f2bf(acc0[g * 4 + 3] * inv);
    *(ushort4*)(Orow + 8 * g + 4 * hi) = o4;
  }
#pragma unroll
  for (int g = 0; g < 4; ++g) {
    ushort4 o4;
    o4.x = f2bf(acc1[g * 4 + 0] * inv);
    o4.y = f2bf(acc1[g * 4 + 1] * inv);
    o4.z = f2bf(acc1[g * 4 + 2] * inv);
    o4.w = f2bf(acc1[g * 4 + 3] * inv);
    *(ushort4*)(Orow + 32 + 8 * g + 4 * hi) = o4;
  }
}

// ---------------- launcher ----------------
extern "C" void kernel_launch(void* const* d_in, const int* in_sizes, int n_in,
                              void* d_out, int out_size, void* d_ws, size_t ws_size,
                              hipStream_t stream) {
  const float* x  = (const float*)d_in[0];
  const float* wq = (const float*)d_in[1];
  const float* wk = (const float*)d_in[2];
  const float* wv = (const float*)d_in[3];
  const float* wo = (const float*)d_in[4];
  const float* ob = (const float*)d_in[5];
  float* out = (float*)d_out;

  char* ws = (char*)d_ws;
  u16* Xb    = (u16*)(ws);                              // slot A: Xb then Ab
  u16* Ab    = (u16*)(ws);
  u16* Qb    = (u16*)(ws + (size_t)16 * 1024 * 1024);   // 16 MB
  u16* KPb   = (u16*)(ws + (size_t)32 * 1024 * 1024);   // 16 MB
  u16* VPb   = (u16*)(ws + (size_t)48 * 1024 * 1024);   // 16 MB
  u16* WqkvT = (u16*)(ws + (size_t)64 * 1024 * 1024);   // 6 MB
  u16* WoT   = (u16*)(ws + (size_t)70 * 1024 * 1024);   // 2 MB

  // fused prep: X convert (8192 blocks) + 4 weight transposes (4096 blocks)
  prep_kernel<<<dim3(12288), 256, 0, stream>>>(x, Xb, wq, wk, wv, wo, WqkvT, WoT);

  // fused QKV projection [8192,1024]x[1024,3072] with fused Q/K/V pack epilogue
  gemm_qkv_kernel<<<dim3(1536), 256, 0, stream>>>(Xb, WqkvT, Qb, KPb, VPb);

  attn_kernel<<<dim3(1024), 256, 0, stream>>>(Qb, KPb, VPb, Ab);

  // out projection [8192,1024]x[1024,1024] + bias, fp32 out
  gemm_out_kernel<<<dim3(512), 256, 0, stream>>>(Ab, WoT, out, ob);
}